// Round 13
// baseline (480.071 us; speedup 1.0000x reference)
//
#include <hip/hip_runtime.h>
#include <hip/hip_bf16.h>

using bf16 = __hip_bfloat16;
typedef __attribute__((ext_vector_type(8))) short short8;
typedef __attribute__((ext_vector_type(4))) short short4v;
typedef __attribute__((ext_vector_type(4))) float f32x4;

constexpr int BB = 8;
constexpr int NN = 2048;
constexpr int CC = 256;
constexpr int NTOK = BB * NN;  // 16384
constexpr float TWO_PI = 6.283185307179586f;
constexpr float LOG2_1E4 = 13.287712379549449f;

__device__ __forceinline__ float gelu_f(float x) {
  return 0.5f * x * (1.0f + erff(x * 0.7071067811865475f));
}
__device__ __forceinline__ float us2f(unsigned short u) {
  return __uint_as_float(((unsigned)u) << 16);
}
__device__ __forceinline__ int xcd_swz(int f, int nwg) {
  return (f & 7) * (nwg >> 3) + (f >> 3);
}

template <int T>
__device__ __forceinline__ void stats_rows(const float (*buf)[CC], float* mu, float* rs, float eps) {
  __syncthreads();
  int w = threadIdx.x >> 6, l = threadIdx.x & 63;
  if (w < T) {
    float s = 0.f, s2 = 0.f;
#pragma unroll
    for (int j = 0; j < 4; ++j) { float v = buf[w][l + 64 * j]; s += v; s2 += v * v; }
#pragma unroll
    for (int o = 32; o; o >>= 1) { s += __shfl_down(s, o); s2 += __shfl_down(s2, o); }
    if (l == 0) {
      float m = s * (1.f / 256.f);
      float var = fmaxf(s2 * (1.f / 256.f) - m * m, 0.f);
      mu[w] = m; rs[w] = rsqrtf(var + eps);
    }
  }
  __syncthreads();
}

// ---------------- shared MFMA GEMM core (XOR-swizzled LDS) ------------------
#define GLD16(src, dst)                                                       \
  __builtin_amdgcn_global_load_lds(                                           \
      (const __attribute__((address_space(1))) void*)(src),                   \
      (__attribute__((address_space(3))) void*)(dst), 16, 0, 0)

template <int K, int MI, int NB>
__device__ __forceinline__ void gemm_core(
    const bf16* __restrict__ Ap, int lda, const bf16* __restrict__ Bp,
    bf16 (&As)[NB][MI * 32 * 64], bf16 (&Bs)[NB][64 * 64], f32x4 (&acc)[MI][2]) {
  const int tid = threadIdx.x;
  const int w = tid >> 6, l = tid & 63;
  const int srow = l >> 3;
  const int scol = ((l & 7) ^ srow) * 8;
  const int rsw = (l & 7) * 8;
  const int wm = w >> 1, wn = w & 1;

  auto stage_tile = [&](int buf, int kt) {
#pragma unroll
    for (int i = 0; i < MI; ++i) {
      int r = (w * MI + i) * 8 + srow;
      GLD16(Ap + (long)r * lda + kt + scol, &As[buf][(w * MI + i) * 512 + l * 8]);
    }
#pragma unroll
    for (int i = 0; i < 2; ++i) {
      int r = (w * 2 + i) * 8 + srow;
      GLD16(Bp + (long)r * K + kt + scol, &Bs[buf][(w * 2 + i) * 512 + l * 8]);
    }
  };
  auto compute = [&](int buf) {
    short8 bfr[2][2];
#pragma unroll
    for (int ni = 0; ni < 2; ++ni)
#pragma unroll
      for (int ks = 0; ks < 2; ++ks)
        bfr[ni][ks] = *(const short8*)&Bs[buf][(wn * 32 + ni * 16 + (l & 15)) * 64 +
                                               ((ks * 32 + (l >> 4) * 8) ^ rsw)];
#pragma unroll
    for (int mi = 0; mi < MI; ++mi) {
#pragma unroll
      for (int ks = 0; ks < 2; ++ks) {
        short8 afr = *(const short8*)&As[buf][(wm * (MI * 16) + mi * 16 + (l & 15)) * 64 +
                                              ((ks * 32 + (l >> 4) * 8) ^ rsw)];
#pragma unroll
        for (int ni = 0; ni < 2; ++ni)
          acc[mi][ni] = __builtin_amdgcn_mfma_f32_16x16x32_bf16(afr, bfr[ni][ks], acc[mi][ni], 0, 0, 0);
      }
    }
  };

  if constexpr (NB == 2) {
    stage_tile(0, 0);
    asm volatile("s_waitcnt vmcnt(0)" ::: "memory");
    __builtin_amdgcn_s_barrier();
    int cur = 0;
    for (int kt = 0; kt < K; kt += 64) {
      const bool more = (kt + 64 < K);
      if (more) stage_tile(cur ^ 1, kt + 64);
      compute(cur);
      if (more) asm volatile("s_waitcnt vmcnt(0)" ::: "memory");
      __builtin_amdgcn_s_barrier();
      cur ^= 1;
    }
  } else {
    for (int kt = 0; kt < K; kt += 64) {
      stage_tile(0, kt);
      __syncthreads();
      compute(0);
      __syncthreads();
    }
  }
}

// ---------------- wide row-resident primitives (BM=64, N up to 256) ---------
// Stage an R x 64 bf16 tile (R rows of a [*, ld] matrix starting at src) into
// LDS with the XOR swizzle; layout dst[row*64 + (col ^ ((row&7)*8))].
template <int R>
__device__ __forceinline__ void stage_gB(const bf16* __restrict__ src, int ld, bf16* dst) {
  const int tid = threadIdx.x;
#pragma unroll
  for (int it = 0; it < R / 32; ++it) {
    int chunk = it * 256 + tid;
    int row = chunk >> 3;
    int sc = ((chunk & 7) ^ (row & 7)) * 8;
    GLD16(src + (long)row * ld + sc, dst + chunk * 8);
  }
}

// acc[4][NI]: 64 rows x NI*64 cols; wave w owns cols [w*NI*16*? ...] — wave w
// covers cols w*(NI*16) .. +NI*16-1 per ni block of 16.
template <int NI>
__device__ __forceinline__ void compute_wide(
    const bf16* __restrict__ As, const bf16* __restrict__ Bs, f32x4 (&acc)[4][NI]) {
  const int l = threadIdx.x & 63, w = threadIdx.x >> 6;
  const int rsw = (l & 7) * 8;
  short8 bfr[NI][2];
#pragma unroll
  for (int ni = 0; ni < NI; ++ni)
#pragma unroll
    for (int ks = 0; ks < 2; ++ks)
      bfr[ni][ks] = *(const short8*)&Bs[(w * (NI * 16) + ni * 16 + (l & 15)) * 64 +
                                        ((ks * 32 + (l >> 4) * 8) ^ rsw)];
#pragma unroll
  for (int mi = 0; mi < 4; ++mi)
#pragma unroll
    for (int ks = 0; ks < 2; ++ks) {
      short8 afr = *(const short8*)&As[(mi * 16 + (l & 15)) * 64 +
                                       ((ks * 32 + (l >> 4) * 8) ^ rsw)];
#pragma unroll
      for (int ni = 0; ni < NI; ++ni)
        acc[mi][ni] = __builtin_amdgcn_mfma_f32_16x16x32_bf16(afr, bfr[ni][ks], acc[mi][ni], 0, 0, 0);
    }
}

// Store acc into ktile LDS buffer (4-ktile layout, swizzled) with activation.
// MODE: 0 plain, 1 gelu, 2 bias+gelu, 3 rank1+gelu (badd=rank1 vec, pvec per row)
template <int NI, int MODE>
__device__ __forceinline__ void store_t(
    f32x4 (&acc)[4][NI], const float* __restrict__ badd,
    const float* __restrict__ pvec, int m0, bf16* tb) {
  const int l = threadIdx.x & 63, w = threadIdx.x >> 6;
#pragma unroll
  for (int mi = 0; mi < 4; ++mi)
#pragma unroll
    for (int ni = 0; ni < NI; ++ni) {
      int col = w * (NI * 16) + ni * 16 + (l & 15);
      float bv = (MODE >= 2) ? badd[col] : 0.f;
#pragma unroll
      for (int r = 0; r < 4; ++r) {
        int row = mi * 16 + (l >> 4) * 4 + r;
        float v = acc[mi][ni][r];
        if constexpr (MODE == 2) v += bv;
        if constexpr (MODE == 3) v += pvec[m0 + row] * bv;
        if constexpr (MODE >= 1) v = gelu_f(v);
        bf16 o = __float2bfloat16(v);
        tb[(col >> 6) * 4096 + row * 64 + ((col & 63) ^ ((row & 7) * 8))] = o;
      }
    }
}

// LayerNorm 64 rows of f32 [*,256] into ktile LDS (bf16, swizzled).
__device__ __forceinline__ void ln_to_lds(
    const float* __restrict__ xin, int m0, const float* __restrict__ g,
    const float* __restrict__ b, bf16* hb) {
  const int t = threadIdx.x;
  const int row = t >> 2, seg = (t & 3) * 64;
  const float* xr = xin + (long)(m0 + row) * 256 + seg;
  float xv[64];
  float s = 0.f, s2 = 0.f;
#pragma unroll
  for (int i = 0; i < 16; ++i) {
    float4 v4 = *(const float4*)&xr[i * 4];
    xv[i * 4] = v4.x; xv[i * 4 + 1] = v4.y; xv[i * 4 + 2] = v4.z; xv[i * 4 + 3] = v4.w;
    s += v4.x + v4.y + v4.z + v4.w;
    s2 += v4.x * v4.x + v4.y * v4.y + v4.z * v4.z + v4.w * v4.w;
  }
  s += __shfl_xor(s, 1); s2 += __shfl_xor(s2, 1);
  s += __shfl_xor(s, 2); s2 += __shfl_xor(s2, 2);
  float m = s * (1.f / 256.f);
  float rsv = rsqrtf(fmaxf(s2 * (1.f / 256.f) - m * m, 0.f) + 1e-5f);
#pragma unroll
  for (int i = 0; i < 32; ++i) {
    int c0 = seg + i * 2;
    float v0 = (xv[i * 2] - m) * rsv * g[c0] + b[c0];
    float v1 = (xv[i * 2 + 1] - m) * rsv * g[c0 + 1] + b[c0 + 1];
    bf16 b0 = __float2bfloat16(v0), b1 = __float2bfloat16(v1);
    unsigned u = (unsigned)*(unsigned short*)&b0 | ((unsigned)*(unsigned short*)&b1 << 16);
    *(unsigned*)&hb[(c0 >> 6) * 4096 + row * 64 + ((c0 & 63) ^ ((row & 7) * 8))] = u;
  }
}

// ---------------- fused kernels ---------------------------------------------
// FFN: x3 = (gelu(x2b@W1 + bf1)) @ W2 + bf2 + x2    [t1 stays in LDS]
__global__ void __launch_bounds__(256) k_ffn_fused(
    const bf16* __restrict__ x2b, const float* __restrict__ x2,
    const bf16* __restrict__ W1T, const float* __restrict__ bf1,
    const bf16* __restrict__ W2T, const float* __restrict__ bf2,
    float* __restrict__ x3) {
  __shared__ bf16 As[4096];
  __shared__ bf16 Bs[16384];
  __shared__ bf16 tb[16384];
  const int m0 = blockIdx.x * 64;
  const int l = threadIdx.x & 63, w = threadIdx.x >> 6;
  f32x4 acc[4][4] = {};
  for (int kt = 0; kt < 256; kt += 64) {
    stage_gB<64>(x2b + (long)m0 * 256 + kt, 256, As);
    stage_gB<256>(W1T + kt, 256, Bs);
    __syncthreads();
    compute_wide<4>(As, Bs, acc);
    __syncthreads();
  }
  store_t<4, 2>(acc, bf1, nullptr, 0, tb);
  __syncthreads();
  f32x4 acc2[4][4] = {};
  for (int kt = 0; kt < 4; ++kt) {
    stage_gB<256>(W2T + kt * 64, 256, Bs);
    __syncthreads();
    compute_wide<4>(tb + kt * 4096, Bs, acc2);
    __syncthreads();
  }
#pragma unroll
  for (int mi = 0; mi < 4; ++mi)
#pragma unroll
    for (int ni = 0; ni < 4; ++ni) {
      int col = w * 64 + ni * 16 + (l & 15);
      float bv = bf2[col];
#pragma unroll
      for (int r = 0; r < 4; ++r) {
        long row = m0 + mi * 16 + (l >> 4) * 4 + r;
        x3[row * 256 + col] = acc2[mi][ni][r] + bv + x2[row * 256 + col];
      }
    }
}

// Propagator: h=LN(x3); p1=gelu(h@P1+pvec*P1L); p2=gelu(p1@P2); zp=p2@P3+x3
__global__ void __launch_bounds__(256) k_prop_fused(
    const float* __restrict__ x3, const float* __restrict__ lng,
    const float* __restrict__ lnb, const bf16* __restrict__ P1T,
    const float* __restrict__ P1L, const float* __restrict__ pvec,
    const bf16* __restrict__ P2T, const bf16* __restrict__ P3T,
    float* __restrict__ zp, bf16* __restrict__ zpb) {
  __shared__ bf16 Bs[16384];
  __shared__ bf16 tb[16384];
  const int m0 = blockIdx.x * 64;
  const int l = threadIdx.x & 63, w = threadIdx.x >> 6;
  ln_to_lds(x3, m0, lng, lnb, tb);
  __syncthreads();
  f32x4 acc[4][4] = {};
  for (int kt = 0; kt < 4; ++kt) {
    stage_gB<256>(P1T + kt * 64, 256, Bs);
    __syncthreads();
    compute_wide<4>(tb + kt * 4096, Bs, acc);
    __syncthreads();
  }
  store_t<4, 3>(acc, P1L, pvec, m0, tb);
  __syncthreads();
  f32x4 acc2[4][4] = {};
  for (int kt = 0; kt < 4; ++kt) {
    stage_gB<256>(P2T + kt * 64, 256, Bs);
    __syncthreads();
    compute_wide<4>(tb + kt * 4096, Bs, acc2);
    __syncthreads();
  }
  store_t<4, 1>(acc2, nullptr, nullptr, 0, tb);
  __syncthreads();
  f32x4 acc3[4][4] = {};
  for (int kt = 0; kt < 4; ++kt) {
    stage_gB<256>(P3T + kt * 64, 256, Bs);
    __syncthreads();
    compute_wide<4>(tb + kt * 4096, Bs, acc3);
    __syncthreads();
  }
#pragma unroll
  for (int mi = 0; mi < 4; ++mi)
#pragma unroll
    for (int ni = 0; ni < 4; ++ni) {
      int col = w * 64 + ni * 16 + (l & 15);
#pragma unroll
      for (int r = 0; r < 4; ++r) {
        long row = m0 + mi * 16 + (l >> 4) * 4 + r;
        float v = acc3[mi][ni][r] + x3[row * 256 + col];
        zp[row * 256 + col] = v;
        zpb[row * 256 + col] = __float2bfloat16(v);
      }
    }
}

// Decode attn: att = q2r @ dots2T[b]; zd = att @ Woda + boda + zp
__global__ void __launch_bounds__(256) k_attdec_fused(
    const bf16* __restrict__ q2b, const bf16* __restrict__ dots2T,
    const bf16* __restrict__ WodaT, const float* __restrict__ boda,
    const float* __restrict__ zp, float* __restrict__ zd) {
  __shared__ bf16 As[4096];
  __shared__ bf16 Bs[16384];
  __shared__ bf16 tb[16384];
  const int m0 = blockIdx.x * 64;
  const int l = threadIdx.x & 63, w = threadIdx.x >> 6;
  const bf16* Bp = dots2T + (long)(m0 >> 11) * 65536;
  f32x4 acc[4][4] = {};
  for (int kt = 0; kt < 256; kt += 64) {
    stage_gB<64>(q2b + (long)m0 * 256 + kt, 256, As);
    stage_gB<256>(Bp + kt, 256, Bs);
    __syncthreads();
    compute_wide<4>(As, Bs, acc);
    __syncthreads();
  }
  store_t<4, 0>(acc, nullptr, nullptr, 0, tb);
  __syncthreads();
  f32x4 acc2[4][4] = {};
  for (int kt = 0; kt < 4; ++kt) {
    stage_gB<256>(WodaT + kt * 64, 256, Bs);
    __syncthreads();
    compute_wide<4>(tb + kt * 4096, Bs, acc2);
    __syncthreads();
  }
#pragma unroll
  for (int mi = 0; mi < 4; ++mi)
#pragma unroll
    for (int ni = 0; ni < 4; ++ni) {
      int col = w * 64 + ni * 16 + (l & 15);
      float bv = boda[col];
#pragma unroll
      for (int r = 0; r < 4; ++r) {
        long row = m0 + mi * 16 + (l >> 4) * 4 + r;
        zd[row * 256 + col] = acc2[mi][ni][r] + bv + zp[row * 256 + col];
      }
    }
}

// Decode MLP: h2=LN(zd); g1=gelu(h2@D1); g2=gelu(g1@D2); u=g2@D3+b3
__global__ void __launch_bounds__(256) k_dec_fused(
    const float* __restrict__ zd, const float* __restrict__ ln2g,
    const float* __restrict__ ln2b, const bf16* __restrict__ D1T,
    const bf16* __restrict__ D2T, const float* __restrict__ D3,
    const float* __restrict__ b3, float* __restrict__ u) {
  __shared__ bf16 Bs[16384];
  __shared__ bf16 tb[16384];
  const int m0 = blockIdx.x * 64;
  const int l = threadIdx.x & 63, w = threadIdx.x >> 6;
  ln_to_lds(zd, m0, ln2g, ln2b, tb);
  __syncthreads();
  f32x4 acc[4][4] = {};
  for (int kt = 0; kt < 4; ++kt) {
    stage_gB<256>(D1T + kt * 64, 256, Bs);
    __syncthreads();
    compute_wide<4>(tb + kt * 4096, Bs, acc);
    __syncthreads();
  }
  store_t<4, 1>(acc, nullptr, nullptr, 0, tb);
  __syncthreads();
  f32x4 acc2[4][2] = {};
  for (int kt = 0; kt < 4; ++kt) {
    stage_gB<128>(D2T + kt * 64, 256, Bs);
    __syncthreads();
    compute_wide<2>(tb + kt * 4096, Bs, acc2);
    __syncthreads();
  }
  // g2 (64x128) linear into Bs region
#pragma unroll
  for (int mi = 0; mi < 4; ++mi)
#pragma unroll
    for (int ni = 0; ni < 2; ++ni) {
      int col = w * 32 + ni * 16 + (l & 15);
#pragma unroll
      for (int r = 0; r < 4; ++r) {
        int row = mi * 16 + (l >> 4) * 4 + r;
        Bs[row * 128 + col] = __float2bfloat16(gelu_f(acc2[mi][ni][r]));
      }
    }
  __syncthreads();
  const int t = threadIdx.x;
  const int row = t >> 2, seg = (t & 3) * 32;
  float s = 0.f;
#pragma unroll
  for (int i = 0; i < 32; ++i)
    s += __bfloat162float(Bs[row * 128 + seg + i]) * D3[seg + i];
  s += __shfl_xor(s, 1);
  s += __shfl_xor(s, 2);
  if ((t & 3) == 0) u[m0 + row] = s + b3[0];
}

// ---------------- k_gemm with fused epilogues (BM=128, BN=64) ---------------
enum { E_BF16 = 0, E_BIAS_RESB_BOTH };

template <int K, int EPI>
__global__ void __launch_bounds__(256) k_gemm(
    const bf16* __restrict__ A, int lda, const bf16* __restrict__ Bt,
    long bstride, long zstride, int nOffZ,
    const float* __restrict__ bias, const bf16* __restrict__ resB,
    float* __restrict__ outF, bf16* __restrict__ outB, int ldo) {
  __shared__ bf16 As[1][128 * 64];
  __shared__ bf16 Bs[1][64 * 64];
  const int tid = threadIdx.x;
  const int w = tid >> 6, l = tid & 63;
  const int m0 = blockIdx.y * 128, n0 = blockIdx.x * 64;
  const int bidx = m0 >> 11;
  const bf16* Bp = Bt + (long)bidx * bstride + (long)blockIdx.z * zstride + (long)n0 * K;
  f32x4 acc[4][2] = {};
  gemm_core<K, 4, 1>(A + (long)m0 * lda, lda, Bp, As, Bs, acc);
  const int wm = w >> 1, wn = w & 1;
  const int zoff = blockIdx.z * nOffZ;
#pragma unroll
  for (int mi = 0; mi < 4; ++mi) {
#pragma unroll
    for (int ni = 0; ni < 2; ++ni) {
      const int bcol = n0 + wn * 32 + ni * 16 + (l & 15);
      const int ocol = bcol + zoff;
#pragma unroll
      for (int r = 0; r < 4; ++r) {
        const int row = m0 + wm * 64 + mi * 16 + (l >> 4) * 4 + r;
        float v = acc[mi][ni][r];
        const long oidx = (long)row * ldo + ocol;
        if constexpr (EPI == E_BF16) {
          outB[oidx] = __float2bfloat16(v);
        } else {  // E_BIAS_RESB_BOTH
          v += bias[bcol] + __bfloat162float(resB[oidx]);
          outF[oidx] = v; outB[oidx] = __float2bfloat16(v);
        }
      }
    }
  }
}

// ---------------- k_gemmT: GEMM with TRANSPOSED per-matrix output ----------
template <int K>
__global__ void __launch_bounds__(256) k_gemmT(
    const bf16* __restrict__ A, int lda, const bf16* __restrict__ Bt, int nx,
    bf16* __restrict__ T0, bf16* __restrict__ T1, int thresh, int matsPerB) {
  __shared__ union {
    struct { bf16 A[1][128 * 64]; bf16 B[1][64 * 64]; } ab;
    bf16 stage[64 * 132];
  } sm;
  const int tid = threadIdx.x;
  const int w = tid >> 6, l = tid & 63;
  const int f = xcd_swz(blockIdx.x, gridDim.x);
  const int n0 = (f % nx) * 64;
  const int m0 = (f / nx) * 128;
  f32x4 acc[4][2] = {};
  gemm_core<K, 4, 1>(A + (long)m0 * lda, lda, Bt + (long)n0 * K, sm.ab.A, sm.ab.B, acc);
  const int wm = w >> 1, wn = w & 1;
  __syncthreads();
#pragma unroll
  for (int mi = 0; mi < 4; ++mi)
#pragma unroll
    for (int ni = 0; ni < 2; ++ni) {
      int c = wn * 32 + ni * 16 + (l & 15);
      int row0 = wm * 64 + mi * 16 + (l >> 4) * 4;
#pragma unroll
      for (int q = 0; q < 2; ++q) {
        bf16 b0 = __float2bfloat16(acc[mi][ni][2 * q]);
        bf16 b1 = __float2bfloat16(acc[mi][ni][2 * q + 1]);
        unsigned u = (unsigned)*(unsigned short*)&b0 |
                     ((unsigned)*(unsigned short*)&b1 << 16);
        *(unsigned*)&sm.stage[c * 132 + row0 + 2 * q] = u;
      }
    }
  __syncthreads();
  const int b = m0 >> 11, nbase = m0 & 2047;
  const int part = (n0 >= thresh) ? 1 : 0;
  const int cT0 = n0 - (part ? thresh : 0);
  bf16* dst = (part ? T1 : T0) + ((long)(b * matsPerB + (cT0 >> 8))) * 524288
            + (long)(cT0 & 255) * 2048;
  const int c = tid >> 2, ns = tid & 3;
  bf16* rowp = dst + (long)c * 2048 + nbase + ns * 8;
#pragma unroll
  for (int j = 0; j < 4; ++j) {
    short4v lo = *(const short4v*)&sm.stage[c * 132 + ns * 8 + j * 32];
    short4v hi = *(const short4v*)&sm.stage[c * 132 + ns * 8 + j * 32 + 4];
    short8 v;
    v[0] = lo[0]; v[1] = lo[1]; v[2] = lo[2]; v[3] = lo[3];
    v[4] = hi[0]; v[5] = hi[1]; v[6] = hi[2]; v[7] = hi[3];
    *(short8*)&rowp[j * 32] = v;
  }
}

// ---------------- k_atb2: D[mat] = A[mat] * B[mat]^T ------------------------
__global__ void __launch_bounds__(256) k_atb2(
    const bf16* __restrict__ A0, const bf16* __restrict__ B0,
    bf16* __restrict__ D0, float scale) {
  __shared__ bf16 As[2][2 * 32 * 64];
  __shared__ bf16 Bs[2][64 * 64];
  const int tid = threadIdx.x;
  const int w = tid >> 6, l = tid & 63;
  const int f = xcd_swz(blockIdx.x, gridDim.x);
  const int n0 = (f & 3) * 64;
  const int m0 = ((f >> 2) & 3) * 64;
  const int mat = f >> 4;
  const bf16* Ap = A0 + (long)mat * 524288 + (long)m0 * 2048;
  const bf16* Bp = B0 + (long)mat * 524288 + (long)n0 * 2048;
  f32x4 acc[2][2] = {};
  gemm_core<2048, 2, 2>(Ap, 2048, Bp, As, Bs, acc);
  bf16* D = D0 + (long)mat * 65536;
  const int wm = w >> 1, wn = w & 1;
#pragma unroll
  for (int mi = 0; mi < 2; ++mi)
#pragma unroll
    for (int ni = 0; ni < 2; ++ni) {
      int col = n0 + wn * 32 + ni * 16 + (l & 15);
#pragma unroll
      for (int r = 0; r < 4; ++r) {
        int row = m0 + wm * 32 + mi * 16 + (l >> 4) * 4 + r;
        D[(long)row * 256 + col] = __float2bfloat16(acc[mi][ni][r] * scale);
      }
    }
}

// ---------------- k_normrot: FUSED stats + norm + rotary on Kt[mat] ---------
__global__ void __launch_bounds__(256) k_normrot(
    bf16* __restrict__ Kt, const bf16* __restrict__ csT, int hshift) {
  __shared__ bf16 tile[256][68];
  __shared__ float ps[4][64], ps2[4][64];
  __shared__ float smu[64], srs[64];
  const int mat = blockIdx.y;
  const int tok0 = blockIdx.x * 64;
  const int b = mat >> hshift;
  const int tid = threadIdx.x;
  bf16* base = Kt + (long)mat * 524288 + tok0;
  const int cr = tid >> 3;
  const int cj = (tid & 7) * 8;
#pragma unroll
  for (int g = 0; g < 8; ++g) {
    int c = g * 32 + cr;
    *(short8*)&tile[c][cj] = *(const short8*)&base[(long)c * 2048 + cj];
  }
  __syncthreads();
  {
    const int tk = tid & 63, q = tid >> 6;
    float s = 0.f, s2 = 0.f;
#pragma unroll 8
    for (int cc = 0; cc < 64; ++cc) {
      float v = us2f(*(const unsigned short*)&tile[q * 64 + cc][tk]);
      s += v; s2 += v * v;
    }
    ps[q][tk] = s; ps2[q][tk] = s2;
  }
  __syncthreads();
  if (tid < 64) {
    float s = ps[0][tid] + ps[1][tid] + ps[2][tid] + ps[3][tid];
    float s2 = ps2[0][tid] + ps2[1][tid] + ps2[2][tid] + ps2[3][tid];
    float m = s * (1.f / 256.f);
    smu[tid] = m;
    srs[tid] = rsqrtf(fmaxf(s2 * (1.f / 256.f) - m * m, 0.f) + 1e-5f);
  }
  __syncthreads();
  const long ctok = (long)b * 2048 + tok0 + cj;
#pragma unroll
  for (int g = 0; g < 4; ++g) {
    int c = g * 32 + cr;
    short8 v0 = *(const short8*)&tile[c][cj];
    short8 v1 = *(const short8*)&tile[c + 128][cj];
    const bf16* cop = csT + (long)(c * 2) * 16384 + ctok;
    short8 co8 = *(const short8*)cop;
    short8 si8 = *(const short8*)(cop + 16384);
    short8 o0, o1;
#pragma unroll
    for (int e = 0; e < 8; ++e) {
      float m = smu[cj + e], r = srs[cj + e];
      float a = (us2f((unsigned short)v0[e]) - m) * r;
      float bb = (us2f((unsigned short)v1[e]) - m) * r;
      float co = us2f((unsigned short)co8[e]);
      float si = us2f((unsigned short)si8[e]);
      bf16 t0 = __float2bfloat16(a * co - bb * si);
      bf16 t1 = __float2bfloat16(bb * co + a * si);
      o0[e] = *(short*)&t0; o1[e] = *(short*)&t1;
    }
    *(short8*)&base[(long)c * 2048 + cj] = o0;
    *(short8*)&base[(long)(c + 128) * 2048 + cj] = o1;
  }
}

// token-major instnorm + rotary (4 tokens/block); in may equal out
__global__ void __launch_bounds__(256) k_rotq(
    const bf16* __restrict__ in, bf16* __restrict__ out, const bf16* __restrict__ cs) {
  __shared__ float xr[4][CC];
  __shared__ float mu[4], rs[4];
  int tid = threadIdx.x;
  long tok0 = (long)blockIdx.x * 4;
#pragma unroll
  for (int t = 0; t < 4; ++t) xr[t][tid] = __bfloat162float(in[(tok0 + t) * 256 + tid]);
  stats_rows<4>(xr, mu, rs, 1e-5f);
  int i = tid & 127;
#pragma unroll
  for (int t = 0; t < 4; ++t) {
    float co = __bfloat162float(cs[(tok0 + t) * 256 + i]);
    float si = __bfloat162float(cs[(tok0 + t) * 256 + 128 + i]);
    float n0 = (xr[t][tid] - mu[t]) * rs[t];
    float n1 = (xr[t][tid ^ 128] - mu[t]) * rs[t];
    float o = (tid < 128) ? (n0 * co - n1 * si) : (n0 * co + n1 * si);
    out[(tok0 + t) * 256 + tid] = __float2bfloat16(o);
  }
}

// ---------------- weight prep ------------------------------------------------
struct WEnt { const float* s; bf16* d; int K; int N; int blk0; };
struct WTab { WEnt e[12]; };

__global__ void __launch_bounds__(256) k_wprep(WTab t) {
  int bid = blockIdx.x;
  int ei = 0;
#pragma unroll
  for (int i = 1; i < 12; ++i)
    if (bid >= t.e[i].blk0) ei = i;
  WEnt e = t.e[ei];
  int local = (bid - e.blk0) * 256 + threadIdx.x;
  if (local < e.K * e.N) {
    int n = local / e.K, k = local - n * e.K;
    e.d[local] = __float2bfloat16(e.s[(long)k * e.N + n]);
  }
}

__global__ void __launch_bounds__(256) k_csT(
    const float* __restrict__ pos, bf16* __restrict__ csT) {
  const int c = blockIdx.y;
  const int n = blockIdx.x * 256 + threadIdx.x;
  float inv = exp2f(-((float)c * (1.f / 128.f)) * LOG2_1E4);
  float fh = pos[n] * 2048.f * inv;
  float s, co; sincosf(fh, &s, &co);
  csT[(long)(c * 2) * 16384 + n] = __float2bfloat16(co);
  csT[(long)(c * 2 + 1) * 16384 + n] = __float2bfloat16(s);
}

__global__ void __launch_bounds__(256) k_pre(
    const float* __restrict__ pos, const float* __restrict__ Bf,
    const float* __restrict__ z, const float* __restrict__ P1,
    bf16* __restrict__ gf, bf16* __restrict__ cs,
    float* __restrict__ pvec, bf16* __restrict__ zb, float* __restrict__ P1L) {
  int tid = threadIdx.x;
  long tok0 = (long)blockIdx.x * 4;
  if (blockIdx.x == 0) P1L[tid] = P1[65536 + tid];
  float p[4];
#pragma unroll
  for (int t = 0; t < 4; ++t) p[t] = pos[tok0 + t];
  if (tid < 4) pvec[tok0 + tid] = p[tid] * 0.0625f;
  float bfc = Bf[tid];
#pragma unroll
  for (int t = 0; t < 4; ++t) {
    float xp = TWO_PI * (p[t] * 0.0625f) * bfc;
    float s, c; sincosf(xp, &s, &c);
    gf[(tok0 + t) * 512 + tid] = __float2bfloat16(gelu_f(s));
    gf[(tok0 + t) * 512 + 256 + tid] = __float2bfloat16(gelu_f(c));
    zb[(tok0 + t) * 256 + tid] = __float2bfloat16(z[(tok0 + t) * 256 + tid]);
  }
  if (tid < 128) {
    float inv = exp2f(-((float)tid * (1.f / 128.f)) * LOG2_1E4);
#pragma unroll
    for (int t = 0; t < 4; ++t) {
      float fh = p[t] * 2048.f * inv;
      float s, c; sincosf(fh, &s, &c);
      cs[(tok0 + t) * 256 + tid] = __float2bfloat16(c);
      cs[(tok0 + t) * 256 + 128 + tid] = __float2bfloat16(s);
    }
  }
}

// ======================= launcher ===========================================
extern "C" void kernel_launch(void* const* d_in, const int* in_sizes, int n_in,
                              void* d_out, int out_size, void* d_ws, size_t ws_size,
                              hipStream_t stream) {
  const float* z    = (const float*)d_in[0];
  const float* pos  = (const float*)d_in[1];
  const float* Bf   = (const float*)d_in[2];
  const float* Wc   = (const float*)d_in[3];
  const float* Wkv  = (const float*)d_in[4];
  const float* Woca = (const float*)d_in[5];
  const float* boca = (const float*)d_in[6];
  const float* Wf1  = (const float*)d_in[7];
  const float* bf1  = (const float*)d_in[8];
  const float* Wf2  = (const float*)d_in[9];
  const float* bf2  = (const float*)d_in[10];
  const float* lng  = (const float*)d_in[11];
  const float* lnb  = (const float*)d_in[12];
  const float* P1   = (const float*)d_in[13];
  const float* P2   = (const float*)d_in[14];
  const float* P3   = (const float*)d_in[15];
  const float* Wqkv = (const float*)d_in[16];
  const float* Woda = (const float*)d_in[17];
  const float* boda = (const float*)d_in[18];
  const float* ln2g = (const float*)d_in[19];
  const float* ln2b = (const float*)d_in[20];
  const float* D1   = (const float*)d_in[21];
  const float* D2   = (const float*)d_in[22];
  const float* D3   = (const float*)d_in[23];
  const float* b3   = (const float*)d_in[24];

  float* u  = (float*)d_out;
  float* zp = (float*)d_out + NTOK;

  const long MB = 1048576L;
  char* ws = (char*)d_ws;
  // ---- static region [0, 24MB) ----
  bf16*  cs   = (bf16*)(ws);
  bf16*  csT  = (bf16*)(ws + 8 * MB);
  float* pvec = (float*)(ws + 16 * MB);
  long wo = 16 * MB + 65536;
  bf16* WcT   = (bf16*)(ws + wo);               wo += 262144;
  bf16* WkvT  = (bf16*)(ws + wo);               wo += 1048576;
  bf16* WocaT = (bf16*)(ws + wo);               wo += 524288;
  bf16* Wf1T  = (bf16*)(ws + wo);               wo += 131072;
  bf16* Wf2T  = (bf16*)(ws + wo);               wo += 131072;
  bf16* P1T   = (bf16*)(ws + wo);               wo += 131072;
  bf16* P2T   = (bf16*)(ws + wo);               wo += 131072;
  bf16* P3T   = (bf16*)(ws + wo);               wo += 131072;
  bf16* WqkvT = (bf16*)(ws + wo);               wo += 393216;
  bf16* WodaT = (bf16*)(ws + wo);               wo += 131072;
  bf16* D1T   = (bf16*)(ws + wo);               wo += 131072;
  bf16* D2T   = (bf16*)(ws + wo);               wo += 65536;
  float* P1L  = (float*)(ws + wo);              wo += 1024;
  // ---- dynamic arena at 24 MB (lifetime audit, W=writer step R=last read;
  //      all overlaps are across sequential launches) ----
  char* AR = ws + 24 * MB;
  bf16*  xb     = (bf16*)(AR);             // [0,8)   W4  R10
  bf16*  zb     = (bf16*)(AR + 8 * MB);    // [8,16)  W2  R5
  bf16*  gf     = (bf16*)(AR + 48 * MB);   // [48,64) W2  R4 (Vt W5 after)
  bf16*  Kt     = (bf16*)(AR + 16 * MB);   // [16,48) W5/6 R7
  bf16*  Vt     = (bf16*)(AR + 48 * MB);   // [48,80) W5  R7
  bf16*  dotsT  = (bf16*)(AR + 8 * MB);    // [8,12)  W7  R9   (zb R5)
  bf16*  qrot   = (bf16*)(AR + 16 * MB);   // [16,24) W8  R9   (Kt R7)
  bf16*  merged = (bf16*)(AR + 24 * MB);   // [24,56) W9  R10  (Kt/Vt R7)
  float* x2     = (float*)(AR + 56 * MB);  // [56,72) W10 R11  (Vt R7)
  bf16*  x2b    = (bf16*)(AR + 72 * MB);   // [72,80) W10 R11
  float* x3     = (float*)(AR + 16 * MB);  // [16,32) W11 R12  (qrot R9)
  bf16*  zpb    = (bf16*)(AR + 32 * MB);   // [32,40) W12 R14  (merged R10)
  bf16*  q2b    = (bf16*)(AR + 40 * MB);   // [40,48) W13/15 R18
  bf16*  k2t    = (bf16*)(AR + 48 * MB);   // [48,56) W14/16 R17 (Vt R7)
  bf16*  v2t    = (bf16*)(AR + 56 * MB);   // [56,64) W14 R17 (x2 R11)
  bf16*  dots2T = (bf16*)(AR + 8 * MB);    // [8,9)   W17 R18 (dotsT R9)
  float* zd     = (float*)(AR + 64 * MB);  // [64,80) W18 R19 (x2/x2b R11)

  // ---- weight-prep table ----
  WTab tab;
  int nb = 0;
  auto add = [&](int i, const float* s, bf16* d, int K_, int N_) {
    tab.e[i].s = s; tab.e[i].d = d; tab.e[i].K = K_; tab.e[i].N = N_;
    tab.e[i].blk0 = nb; nb += (K_ * N_) / 256;
  };
  add(0, Wc, WcT, 512, 256);
  add(1, Wkv, WkvT, 256, 2048);
  add(2, Woca, WocaT, 1024, 256);
  add(3, Wf1, Wf1T, 256, 256);
  add(4, Wf2, Wf2T, 256, 256);
  add(5, P1, P1T, 256, 256);
  add(6, P2, P2T, 256, 256);
  add(7, P3, P3T, 256, 256);
  add(8, Wqkv, WqkvT, 256, 768);
  add(9, Woda, WodaT, 256, 256);
  add(10, D1, D1T, 256, 256);
  add(11, D2, D2T, 256, 128);
  k_wprep<<<nb, 256, 0, stream>>>(tab);                                   // 1

  k_pre<<<NTOK / 4, 256, 0, stream>>>(pos, Bf, z, P1, gf, cs, pvec, zb, P1L);  // 2
  k_csT<<<dim3(NTOK / 256, 128), 256, 0, stream>>>(pos, csT);             // 3
  // 4: x = gelu(fourier) @ WcT
  k_gemm<512, E_BF16><<<dim3(4, 128, 1), 256, 0, stream>>>(
      gf, 512, WcT, 0, 0, 0, nullptr, nullptr, nullptr, xb, 256);
  // 5: Kt/Vt = (z @ Wkv) transposed
  k_gemmT<256><<<32 * 128, 256, 0, stream>>>(zb, 256, WkvT, 32, Kt, Vt, 1024, 4);
  // 6: fused instnorm + rotary on Kt
  k_normrot<<<dim3(32, 32), 256, 0, stream>>>(Kt, csT, 2);
  // 7: dotsT[mat] = Vt * Kt^T / n
  k_atb2<<<512, 256, 0, stream>>>(Vt, Kt, dotsT, 1.f / 2048.f);
  // 8: qrot
  k_rotq<<<NTOK / 4, 256, 0, stream>>>(xb, qrot, cs);
  // 9: merged[:, h*256:] = qrot @ dotsT[b,h]
  k_gemm<256, E_BF16><<<dim3(4, 128, 4), 256, 0, stream>>>(
      qrot, 256, dotsT, 262144L, 65536L, 256, nullptr, nullptr, nullptr, merged, 1024);
  // 10: x2 = merged @ WocaT + boca + x
  k_gemm<1024, E_BIAS_RESB_BOTH><<<dim3(4, 128, 1), 256, 0, stream>>>(
      merged, 1024, WocaT, 0, 0, 0, boca, xb, x2, x2b, 256);
  // 11: FFN fused -> x3
  k_ffn_fused<<<NTOK / 64, 256, 0, stream>>>(x2b, x2, Wf1T, bf1, Wf2T, bf2, x3);
  // 12: LN + propagator fused -> zp, zpb
  k_prop_fused<<<NTOK / 64, 256, 0, stream>>>(x3, lng, lnb, P1T, P1L, pvec,
                                              P2T, P3T, zp, zpb);
  // 13: q2 token-major
  k_gemm<256, E_BF16><<<dim3(4, 128, 1), 256, 0, stream>>>(
      zpb, 256, WqkvT, 0, 0, 0, nullptr, nullptr, nullptr, q2b, 256);
  // 14: k2/v2 transposed
  k_gemmT<256><<<8 * 128, 256, 0, stream>>>(zpb, 256, WqkvT + 65536, 8, k2t, v2t, 256, 1);
  // 15: q2 instnorm+rot in place
  k_rotq<<<NTOK / 4, 256, 0, stream>>>(q2b, q2b, cs);
  // 16: k2 norm+rot
  k_normrot<<<dim3(32, 8), 256, 0, stream>>>(k2t, csT, 0);
  // 17: dots2T
  k_atb2<<<128, 256, 0, stream>>>(v2t, k2t, dots2T, 1.f / 2048.f);
  // 18: att + Woda + residual fused -> zd
  k_attdec_fused<<<NTOK / 64, 256, 0, stream>>>(q2b, dots2T, WodaT, boda, zp, zd);
  // 19: LN2 + decode MLP + matvec fused -> u
  k_dec_fused<<<NTOK / 64, 256, 0, stream>>>(zd, ln2g, ln2b, D1T, D2T, D3, b3, u);
}

// Round 14
// 398.997 us; speedup vs baseline: 1.2032x; 1.2032x over previous
//
#include <hip/hip_runtime.h>
#include <hip/hip_bf16.h>

using bf16 = __hip_bfloat16;
typedef __attribute__((ext_vector_type(8))) short short8;
typedef __attribute__((ext_vector_type(4))) short short4v;
typedef __attribute__((ext_vector_type(4))) float f32x4;

constexpr int BB = 8;
constexpr int NN = 2048;
constexpr int CC = 256;
constexpr int NTOK = BB * NN;  // 16384
constexpr float TWO_PI = 6.283185307179586f;
constexpr float LOG2_1E4 = 13.287712379549449f;

__device__ __forceinline__ float gelu_f(float x) {
  return 0.5f * x * (1.0f + erff(x * 0.7071067811865475f));
}
__device__ __forceinline__ float us2f(unsigned short u) {
  return __uint_as_float(((unsigned)u) << 16);
}
// Bijective XCD-chunk swizzle (requires nwg % 8 == 0).
__device__ __forceinline__ int xcd_swz(int f, int nwg) {
  return (f & 7) * (nwg >> 3) + (f >> 3);
}

template <int T>
__device__ __forceinline__ void stats_rows(const float (*buf)[CC], float* mu, float* rs, float eps) {
  __syncthreads();
  int w = threadIdx.x >> 6, l = threadIdx.x & 63;
  if (w < T) {
    float s = 0.f, s2 = 0.f;
#pragma unroll
    for (int j = 0; j < 4; ++j) { float v = buf[w][l + 64 * j]; s += v; s2 += v * v; }
#pragma unroll
    for (int o = 32; o; o >>= 1) { s += __shfl_down(s, o); s2 += __shfl_down(s2, o); }
    if (l == 0) {
      float m = s * (1.f / 256.f);
      float var = fmaxf(s2 * (1.f / 256.f) - m * m, 0.f);
      mu[w] = m; rs[w] = rsqrtf(var + eps);
    }
  }
  __syncthreads();
}

// ---------------- shared MFMA GEMM core (XOR-swizzled LDS) ------------------
// NB=1: single-buffered (24KB LDS; TLP hides staging; best for K<=512).
// NB=2: double-buffered 2-phase (deep K=2048 loops).
#define GLD16(src, dst)                                                       \
  __builtin_amdgcn_global_load_lds(                                           \
      (const __attribute__((address_space(1))) void*)(src),                   \
      (__attribute__((address_space(3))) void*)(dst), 16, 0, 0)

template <int K, int MI, int NB>
__device__ __forceinline__ void gemm_core(
    const bf16* __restrict__ Ap, int lda, const bf16* __restrict__ Bp,
    bf16 (&As)[NB][MI * 32 * 64], bf16 (&Bs)[NB][64 * 64], f32x4 (&acc)[MI][2]) {
  const int tid = threadIdx.x;
  const int w = tid >> 6, l = tid & 63;
  const int srow = l >> 3;
  const int scol = ((l & 7) ^ srow) * 8;  // swizzled source col
  const int rsw = (l & 7) * 8;            // read-side XOR (row&7 == l&7)
  const int wm = w >> 1, wn = w & 1;

  auto stage_tile = [&](int buf, int kt) {
#pragma unroll
    for (int i = 0; i < MI; ++i) {
      int r = (w * MI + i) * 8 + srow;
      GLD16(Ap + (long)r * lda + kt + scol, &As[buf][(w * MI + i) * 512 + l * 8]);
    }
#pragma unroll
    for (int i = 0; i < 2; ++i) {
      int r = (w * 2 + i) * 8 + srow;
      GLD16(Bp + (long)r * K + kt + scol, &Bs[buf][(w * 2 + i) * 512 + l * 8]);
    }
  };
  auto compute = [&](int buf) {
    short8 bfr[2][2];
#pragma unroll
    for (int ni = 0; ni < 2; ++ni)
#pragma unroll
      for (int ks = 0; ks < 2; ++ks)
        bfr[ni][ks] = *(const short8*)&Bs[buf][(wn * 32 + ni * 16 + (l & 15)) * 64 +
                                               ((ks * 32 + (l >> 4) * 8) ^ rsw)];
#pragma unroll
    for (int mi = 0; mi < MI; ++mi) {
#pragma unroll
      for (int ks = 0; ks < 2; ++ks) {
        short8 afr = *(const short8*)&As[buf][(wm * (MI * 16) + mi * 16 + (l & 15)) * 64 +
                                              ((ks * 32 + (l >> 4) * 8) ^ rsw)];
#pragma unroll
        for (int ni = 0; ni < 2; ++ni)
          acc[mi][ni] = __builtin_amdgcn_mfma_f32_16x16x32_bf16(afr, bfr[ni][ks], acc[mi][ni], 0, 0, 0);
      }
    }
  };

  if constexpr (NB == 2) {
    stage_tile(0, 0);
    asm volatile("s_waitcnt vmcnt(0)" ::: "memory");
    __builtin_amdgcn_s_barrier();
    int cur = 0;
    for (int kt = 0; kt < K; kt += 64) {
      const bool more = (kt + 64 < K);
      if (more) stage_tile(cur ^ 1, kt + 64);
      compute(cur);
      if (more) asm volatile("s_waitcnt vmcnt(0)" ::: "memory");
      __builtin_amdgcn_s_barrier();
      cur ^= 1;
    }
  } else {
    for (int kt = 0; kt < K; kt += 64) {
      stage_tile(0, kt);
      __syncthreads();
      compute(0);
      __syncthreads();
    }
  }
}

// ---------------- k_gemm with fused epilogues (BM=128, BN=64) ---------------
enum { E_BF16 = 0, E_BIAS_RESB_BOTH, E_BIAS_GELU, E_BIAS_RES_F32,
       E_RANK1_GELU, E_GELU, E_RES_BOTH };

template <int K, int EPI>
__global__ void __launch_bounds__(256) k_gemm(
    const bf16* __restrict__ A, int lda, const bf16* __restrict__ Bt,
    long bstride, long zstride, int nOffZ,
    const float* __restrict__ bias, const float* __restrict__ res,
    const bf16* __restrict__ resB, const float* __restrict__ rank1,
    const float* __restrict__ pvec,
    float* __restrict__ outF, bf16* __restrict__ outB, int ldo) {
  __shared__ bf16 As[1][128 * 64];
  __shared__ bf16 Bs[1][64 * 64];
  const int tid = threadIdx.x;
  const int w = tid >> 6, l = tid & 63;
  const int m0 = blockIdx.y * 128, n0 = blockIdx.x * 64;
  const int bidx = m0 >> 11;
  const bf16* Bp = Bt + (long)bidx * bstride + (long)blockIdx.z * zstride + (long)n0 * K;
  f32x4 acc[4][2] = {};
  gemm_core<K, 4, 1>(A + (long)m0 * lda, lda, Bp, As, Bs, acc);
  const int wm = w >> 1, wn = w & 1;
  const int zoff = blockIdx.z * nOffZ;
#pragma unroll
  for (int mi = 0; mi < 4; ++mi) {
#pragma unroll
    for (int ni = 0; ni < 2; ++ni) {
      const int bcol = n0 + wn * 32 + ni * 16 + (l & 15);
      const int ocol = bcol + zoff;
#pragma unroll
      for (int r = 0; r < 4; ++r) {
        const int row = m0 + wm * 64 + mi * 16 + (l >> 4) * 4 + r;
        float v = acc[mi][ni][r];
        const long oidx = (long)row * ldo + ocol;
        if constexpr (EPI == E_BF16) { outB[oidx] = __float2bfloat16(v); }
        else if constexpr (EPI == E_BIAS_RESB_BOTH) {
          v += bias[bcol] + __bfloat162float(resB[oidx]);
          outF[oidx] = v; outB[oidx] = __float2bfloat16(v);
        } else if constexpr (EPI == E_BIAS_GELU) {
          v = gelu_f(v + bias[bcol]); outB[oidx] = __float2bfloat16(v);
        } else if constexpr (EPI == E_BIAS_RES_F32) {
          v += bias[bcol] + res[oidx]; outF[oidx] = v;
        } else if constexpr (EPI == E_RANK1_GELU) {
          v = gelu_f(v + pvec[row] * rank1[bcol]); outB[oidx] = __float2bfloat16(v);
        } else if constexpr (EPI == E_GELU) {
          v = gelu_f(v); outB[oidx] = __float2bfloat16(v);
        } else {  // E_RES_BOTH
          v += res[oidx]; outF[oidx] = v; outB[oidx] = __float2bfloat16(v);
        }
      }
    }
  }
}

// ---------------- k_gemmT: GEMM with TRANSPOSED per-matrix output ----------
template <int K>
__global__ void __launch_bounds__(256) k_gemmT(
    const bf16* __restrict__ A, int lda, const bf16* __restrict__ Bt, int nx,
    bf16* __restrict__ T0, bf16* __restrict__ T1, int thresh, int matsPerB) {
  __shared__ union {
    struct { bf16 A[1][128 * 64]; bf16 B[1][64 * 64]; } ab;
    bf16 stage[64 * 132];
  } sm;
  const int tid = threadIdx.x;
  const int w = tid >> 6, l = tid & 63;
  const int f = xcd_swz(blockIdx.x, gridDim.x);
  const int n0 = (f % nx) * 64;
  const int m0 = (f / nx) * 128;
  f32x4 acc[4][2] = {};
  gemm_core<K, 4, 1>(A + (long)m0 * lda, lda, Bt + (long)n0 * K, sm.ab.A, sm.ab.B, acc);
  const int wm = w >> 1, wn = w & 1;
  __syncthreads();
#pragma unroll
  for (int mi = 0; mi < 4; ++mi)
#pragma unroll
    for (int ni = 0; ni < 2; ++ni) {
      int c = wn * 32 + ni * 16 + (l & 15);
      int row0 = wm * 64 + mi * 16 + (l >> 4) * 4;
#pragma unroll
      for (int q = 0; q < 2; ++q) {
        bf16 b0 = __float2bfloat16(acc[mi][ni][2 * q]);
        bf16 b1 = __float2bfloat16(acc[mi][ni][2 * q + 1]);
        unsigned u = (unsigned)*(unsigned short*)&b0 |
                     ((unsigned)*(unsigned short*)&b1 << 16);
        *(unsigned*)&sm.stage[c * 132 + row0 + 2 * q] = u;
      }
    }
  __syncthreads();
  const int b = m0 >> 11, nbase = m0 & 2047;
  const int part = (n0 >= thresh) ? 1 : 0;
  const int cT0 = n0 - (part ? thresh : 0);
  bf16* dst = (part ? T1 : T0) + ((long)(b * matsPerB + (cT0 >> 8))) * 524288
            + (long)(cT0 & 255) * 2048;
  const int c = tid >> 2, ns = tid & 3;
  bf16* rowp = dst + (long)c * 2048 + nbase + ns * 8;
#pragma unroll
  for (int j = 0; j < 4; ++j) {
    short4v lo = *(const short4v*)&sm.stage[c * 132 + ns * 8 + j * 32];
    short4v hi = *(const short4v*)&sm.stage[c * 132 + ns * 8 + j * 32 + 4];
    short8 v;
    v[0] = lo[0]; v[1] = lo[1]; v[2] = lo[2]; v[3] = lo[3];
    v[4] = hi[0]; v[5] = hi[1]; v[6] = hi[2]; v[7] = hi[3];
    *(short8*)&rowp[j * 32] = v;
  }
}

// ---------------- k_atb2: D[mat] = A[mat] * B[mat]^T ------------------------
__global__ void __launch_bounds__(256) k_atb2(
    const bf16* __restrict__ A0, const bf16* __restrict__ B0,
    bf16* __restrict__ D0, float scale) {
  __shared__ bf16 As[2][2 * 32 * 64];
  __shared__ bf16 Bs[2][64 * 64];
  const int tid = threadIdx.x;
  const int w = tid >> 6, l = tid & 63;
  const int f = xcd_swz(blockIdx.x, gridDim.x);
  const int n0 = (f & 3) * 64;
  const int m0 = ((f >> 2) & 3) * 64;
  const int mat = f >> 4;
  const bf16* Ap = A0 + (long)mat * 524288 + (long)m0 * 2048;
  const bf16* Bp = B0 + (long)mat * 524288 + (long)n0 * 2048;
  f32x4 acc[2][2] = {};
  gemm_core<2048, 2, 2>(Ap, 2048, Bp, As, Bs, acc);
  bf16* D = D0 + (long)mat * 65536;
  const int wm = w >> 1, wn = w & 1;
#pragma unroll
  for (int mi = 0; mi < 2; ++mi)
#pragma unroll
    for (int ni = 0; ni < 2; ++ni) {
      int col = n0 + wn * 32 + ni * 16 + (l & 15);
#pragma unroll
      for (int r = 0; r < 4; ++r) {
        int row = m0 + wm * 32 + mi * 16 + (l >> 4) * 4 + r;
        D[(long)row * 256 + col] = __float2bfloat16(acc[mi][ni][r] * scale);
      }
    }
}

// ---------------- k_normrot: FUSED stats + norm + rotary on Kt[mat] ---------
__global__ void __launch_bounds__(256) k_normrot(
    bf16* __restrict__ Kt, const bf16* __restrict__ csT, int hshift) {
  __shared__ bf16 tile[256][68];
  __shared__ float ps[4][64], ps2[4][64];
  __shared__ float smu[64], srs[64];
  const int mat = blockIdx.y;
  const int tok0 = blockIdx.x * 64;
  const int b = mat >> hshift;
  const int tid = threadIdx.x;
  bf16* base = Kt + (long)mat * 524288 + tok0;
  const int cr = tid >> 3;
  const int cj = (tid & 7) * 8;
#pragma unroll
  for (int g = 0; g < 8; ++g) {
    int c = g * 32 + cr;
    *(short8*)&tile[c][cj] = *(const short8*)&base[(long)c * 2048 + cj];
  }
  __syncthreads();
  {
    const int tk = tid & 63, q = tid >> 6;
    float s = 0.f, s2 = 0.f;
#pragma unroll 8
    for (int cc = 0; cc < 64; ++cc) {
      float v = us2f(*(const unsigned short*)&tile[q * 64 + cc][tk]);
      s += v; s2 += v * v;
    }
    ps[q][tk] = s; ps2[q][tk] = s2;
  }
  __syncthreads();
  if (tid < 64) {
    float s = ps[0][tid] + ps[1][tid] + ps[2][tid] + ps[3][tid];
    float s2 = ps2[0][tid] + ps2[1][tid] + ps2[2][tid] + ps2[3][tid];
    float m = s * (1.f / 256.f);
    smu[tid] = m;
    srs[tid] = rsqrtf(fmaxf(s2 * (1.f / 256.f) - m * m, 0.f) + 1e-5f);
  }
  __syncthreads();
  const long ctok = (long)b * 2048 + tok0 + cj;
#pragma unroll
  for (int g = 0; g < 4; ++g) {
    int c = g * 32 + cr;
    short8 v0 = *(const short8*)&tile[c][cj];
    short8 v1 = *(const short8*)&tile[c + 128][cj];
    const bf16* cop = csT + (long)(c * 2) * 16384 + ctok;
    short8 co8 = *(const short8*)cop;
    short8 si8 = *(const short8*)(cop + 16384);
    short8 o0, o1;
#pragma unroll
    for (int e = 0; e < 8; ++e) {
      float m = smu[cj + e], r = srs[cj + e];
      float a = (us2f((unsigned short)v0[e]) - m) * r;
      float bb = (us2f((unsigned short)v1[e]) - m) * r;
      float co = us2f((unsigned short)co8[e]);
      float si = us2f((unsigned short)si8[e]);
      bf16 t0 = __float2bfloat16(a * co - bb * si);
      bf16 t1 = __float2bfloat16(bb * co + a * si);
      o0[e] = *(short*)&t0; o1[e] = *(short*)&t1;
    }
    *(short8*)&base[(long)c * 2048 + cj] = o0;
    *(short8*)&base[(long)(c + 128) * 2048 + cj] = o1;
  }
}

// token-major instnorm + rotary (4 tokens/block); in may equal out
__global__ void __launch_bounds__(256) k_rotq(
    const bf16* __restrict__ in, bf16* __restrict__ out, const bf16* __restrict__ cs) {
  __shared__ float xr[4][CC];
  __shared__ float mu[4], rs[4];
  int tid = threadIdx.x;
  long tok0 = (long)blockIdx.x * 4;
#pragma unroll
  for (int t = 0; t < 4; ++t) xr[t][tid] = __bfloat162float(in[(tok0 + t) * 256 + tid]);
  stats_rows<4>(xr, mu, rs, 1e-5f);
  int i = tid & 127;
#pragma unroll
  for (int t = 0; t < 4; ++t) {
    float co = __bfloat162float(cs[(tok0 + t) * 256 + i]);
    float si = __bfloat162float(cs[(tok0 + t) * 256 + 128 + i]);
    float n0 = (xr[t][tid] - mu[t]) * rs[t];
    float n1 = (xr[t][tid ^ 128] - mu[t]) * rs[t];
    float o = (tid < 128) ? (n0 * co - n1 * si) : (n0 * co + n1 * si);
    out[(tok0 + t) * 256 + tid] = __float2bfloat16(o);
  }
}

// ---------------- weight prep: 12 transposes, one kernel --------------------
struct WEnt { const float* s; bf16* d; int K; int N; int blk0; };
struct WTab { WEnt e[12]; };

__global__ void __launch_bounds__(256) k_wprep(WTab t) {
  int bid = blockIdx.x;
  int ei = 0;
#pragma unroll
  for (int i = 1; i < 12; ++i)
    if (bid >= t.e[i].blk0) ei = i;
  WEnt e = t.e[ei];
  int local = (bid - e.blk0) * 256 + threadIdx.x;
  if (local < e.K * e.N) {
    int n = local / e.K, k = local - n * e.K;
    e.d[local] = __float2bfloat16(e.s[(long)k * e.N + n]);
  }
}

// ---------------- k_csT: transposed cos/sin table, coalesced writes ---------
__global__ void __launch_bounds__(256) k_csT(
    const float* __restrict__ pos, bf16* __restrict__ csT) {
  const int c = blockIdx.y;
  const int n = blockIdx.x * 256 + threadIdx.x;
  float inv = exp2f(-((float)c * (1.f / 128.f)) * LOG2_1E4);
  float fh = pos[n] * 2048.f * inv;
  float s, co; sincosf(fh, &s, &co);
  csT[(long)(c * 2) * 16384 + n] = __float2bfloat16(co);
  csT[(long)(c * 2 + 1) * 16384 + n] = __float2bfloat16(s);
}

// ---------------- k_pre: fourier feats, token-major cos/sin, pvec, z->bf16 --
__global__ void __launch_bounds__(256) k_pre(
    const float* __restrict__ pos, const float* __restrict__ Bf,
    const float* __restrict__ z, const float* __restrict__ P1,
    bf16* __restrict__ gf, bf16* __restrict__ cs,
    float* __restrict__ pvec, bf16* __restrict__ zb, float* __restrict__ P1L) {
  int tid = threadIdx.x;
  long tok0 = (long)blockIdx.x * 4;
  if (blockIdx.x == 0) P1L[tid] = P1[65536 + tid];
  float p[4];
#pragma unroll
  for (int t = 0; t < 4; ++t) p[t] = pos[tok0 + t];
  if (tid < 4) pvec[tok0 + tid] = p[tid] * 0.0625f;
  float bfc = Bf[tid];
#pragma unroll
  for (int t = 0; t < 4; ++t) {
    float xp = TWO_PI * (p[t] * 0.0625f) * bfc;
    float s, c; sincosf(xp, &s, &c);
    gf[(tok0 + t) * 512 + tid] = __float2bfloat16(gelu_f(s));
    gf[(tok0 + t) * 512 + 256 + tid] = __float2bfloat16(gelu_f(c));
    zb[(tok0 + t) * 256 + tid] = __float2bfloat16(z[(tok0 + t) * 256 + tid]);
  }
  if (tid < 128) {
    float inv = exp2f(-((float)tid * (1.f / 128.f)) * LOG2_1E4);
#pragma unroll
    for (int t = 0; t < 4; ++t) {
      float fh = p[t] * 2048.f * inv;
      float s, c; sincosf(fh, &s, &c);
      cs[(tok0 + t) * 256 + tid] = __float2bfloat16(c);
      cs[(tok0 + t) * 256 + 128 + tid] = __float2bfloat16(s);
    }
  }
}

__global__ void __launch_bounds__(256) k_ln(
    const float* __restrict__ xin, const float* __restrict__ g,
    const float* __restrict__ b, bf16* __restrict__ hout) {
  __shared__ float xr[4][CC];
  __shared__ float mu[4], rs[4];
  int tid = threadIdx.x;
  long tok0 = (long)blockIdx.x * 4;
#pragma unroll
  for (int t = 0; t < 4; ++t) xr[t][tid] = xin[(tok0 + t) * 256 + tid];
  stats_rows<4>(xr, mu, rs, 1e-5f);
  float gv = g[tid], bv = b[tid];
#pragma unroll
  for (int t = 0; t < 4; ++t)
    hout[(tok0 + t) * 256 + tid] = __float2bfloat16((xr[t][tid] - mu[t]) * rs[t] * gv + bv);
}

__global__ void __launch_bounds__(256) k_final(
    const bf16* __restrict__ g2, const float* __restrict__ D3,
    const float* __restrict__ b3, float* __restrict__ u) {
  int w = threadIdx.x >> 6, l = threadIdx.x & 63;
  long tok = (long)blockIdx.x * 4 + w;
  float s = __bfloat162float(g2[tok * 128 + l]) * D3[l]
          + __bfloat162float(g2[tok * 128 + 64 + l]) * D3[64 + l];
#pragma unroll
  for (int o = 32; o; o >>= 1) s += __shfl_down(s, o);
  if (l == 0) u[tok] = s + b3[0];
}

// ======================= launcher ===========================================
extern "C" void kernel_launch(void* const* d_in, const int* in_sizes, int n_in,
                              void* d_out, int out_size, void* d_ws, size_t ws_size,
                              hipStream_t stream) {
  const float* z    = (const float*)d_in[0];
  const float* pos  = (const float*)d_in[1];
  const float* Bf   = (const float*)d_in[2];
  const float* Wc   = (const float*)d_in[3];
  const float* Wkv  = (const float*)d_in[4];
  const float* Woca = (const float*)d_in[5];
  const float* boca = (const float*)d_in[6];
  const float* Wf1  = (const float*)d_in[7];
  const float* bf1  = (const float*)d_in[8];
  const float* Wf2  = (const float*)d_in[9];
  const float* bf2  = (const float*)d_in[10];
  const float* lng  = (const float*)d_in[11];
  const float* lnb  = (const float*)d_in[12];
  const float* P1   = (const float*)d_in[13];
  const float* P2   = (const float*)d_in[14];
  const float* P3   = (const float*)d_in[15];
  const float* Wqkv = (const float*)d_in[16];
  const float* Woda = (const float*)d_in[17];
  const float* boda = (const float*)d_in[18];
  const float* ln2g = (const float*)d_in[19];
  const float* ln2b = (const float*)d_in[20];
  const float* D1   = (const float*)d_in[21];
  const float* D2   = (const float*)d_in[22];
  const float* D3   = (const float*)d_in[23];
  const float* b3   = (const float*)d_in[24];

  float* u  = (float*)d_out;
  float* zp = (float*)d_out + NTOK;

  const long MB = 1048576L;
  char* ws = (char*)d_ws;
  // ---- static region [0, 24MB) ----
  bf16*  cs   = (bf16*)(ws);
  bf16*  csT  = (bf16*)(ws + 8 * MB);
  float* pvec = (float*)(ws + 16 * MB);
  long wo = 16 * MB + 65536;
  bf16* WcT   = (bf16*)(ws + wo);               wo += 262144;
  bf16* WkvT  = (bf16*)(ws + wo);               wo += 1048576;
  bf16* WocaT = (bf16*)(ws + wo);               wo += 524288;
  bf16* Wf1T  = (bf16*)(ws + wo);               wo += 131072;
  bf16* Wf2T  = (bf16*)(ws + wo);               wo += 131072;
  bf16* P1T   = (bf16*)(ws + wo);               wo += 131072;
  bf16* P2T   = (bf16*)(ws + wo);               wo += 131072;
  bf16* P3T   = (bf16*)(ws + wo);               wo += 131072;
  bf16* WqkvT = (bf16*)(ws + wo);               wo += 393216;
  bf16* WodaT = (bf16*)(ws + wo);               wo += 131072;
  bf16* D1T   = (bf16*)(ws + wo);               wo += 131072;
  bf16* D2T   = (bf16*)(ws + wo);               wo += 65536;
  float* P1L  = (float*)(ws + wo);              wo += 1024;
  // ---- dynamic arena at 24 MB (round-12 layout, lifetime-audited) ----
  char* AR = ws + 24 * MB;
  bf16*  xb     = (bf16*)(AR);             // [0,8)   W4  R10
  bf16*  zb     = (bf16*)(AR + 8 * MB);    // [8,16)  W2  R5
  bf16*  gf     = (bf16*)(AR + 48 * MB);   // [48,64) W2  R4 (Vt W5 after)
  bf16*  Kt     = (bf16*)(AR + 16 * MB);   // [16,48) W5/6 R7
  bf16*  Vt     = (bf16*)(AR + 48 * MB);   // [48,80) W5  R7
  bf16*  dotsT  = (bf16*)(AR + 8 * MB);    // [8,12)  W7  R9
  bf16*  qrot   = (bf16*)(AR + 16 * MB);   // [16,24) W8  R9
  bf16*  merged = (bf16*)(AR + 24 * MB);   // [24,56) W9  R10
  float* x2     = (float*)(AR + 56 * MB);  // [56,72) W10 R12 (f32)
  bf16*  x2b    = (bf16*)(AR + 72 * MB);   // [72,80) W10 R11
  bf16*  t1     = (bf16*)(AR + 8 * MB);    // [8,16)  W11 R12
  float* x3     = (float*)(AR + 16 * MB);  // [16,32) W12 R16 (f32)
  bf16*  h      = (bf16*)(AR + 32 * MB);   // [32,40) W13 R14
  bf16*  p1o    = (bf16*)(AR + 40 * MB);   // [40,48) W14 R15
  bf16*  p2o    = (bf16*)(AR + 48 * MB);   // [48,56) W15 R16
  bf16*  zpb    = (bf16*)(AR + 56 * MB);   // [56,64) W16 R18
  bf16*  q2b    = (bf16*)(AR + 64 * MB);   // [64,72) W17/19 R22
  bf16*  k2t    = (bf16*)(AR + 72 * MB);   // [72,80) W18/20 R21
  bf16*  v2t    = (bf16*)(AR + 8 * MB);    // [8,16)  W18 R21
  bf16*  dots2T = (bf16*)(AR + 16 * MB);   // [16,17) W21 R22
  bf16*  att    = (bf16*)(AR + 24 * MB);   // [24,32) W22 R23
  float* zd     = (float*)(AR + 32 * MB);  // [32,48) W23 R24 (f32)
  bf16*  h2     = (bf16*)(AR + 8 * MB);    // [8,16)  W24 R25
  bf16*  g1     = (bf16*)(AR + 16 * MB);   // [16,24) W25 R26
  bf16*  g2     = (bf16*)(AR + 24 * MB);   // [24,28) W26 R27

  // ---- weight-prep table ----
  WTab tab;
  int nb = 0;
  auto add = [&](int i, const float* s, bf16* d, int K_, int N_) {
    tab.e[i].s = s; tab.e[i].d = d; tab.e[i].K = K_; tab.e[i].N = N_;
    tab.e[i].blk0 = nb; nb += (K_ * N_) / 256;
  };
  add(0, Wc, WcT, 512, 256);
  add(1, Wkv, WkvT, 256, 2048);
  add(2, Woca, WocaT, 1024, 256);
  add(3, Wf1, Wf1T, 256, 256);
  add(4, Wf2, Wf2T, 256, 256);
  add(5, P1, P1T, 256, 256);
  add(6, P2, P2T, 256, 256);
  add(7, P3, P3T, 256, 256);
  add(8, Wqkv, WqkvT, 256, 768);
  add(9, Woda, WodaT, 256, 256);
  add(10, D1, D1T, 256, 256);
  add(11, D2, D2T, 256, 128);
  k_wprep<<<nb, 256, 0, stream>>>(tab);

  k_pre<<<NTOK / 4, 256, 0, stream>>>(pos, Bf, z, P1, gf, cs, pvec, zb, P1L);
  k_csT<<<dim3(NTOK / 256, 128), 256, 0, stream>>>(pos, csT);
  // x = gelu(fourier) @ WcT
  k_gemm<512, E_BF16><<<dim3(4, 128, 1), 256, 0, stream>>>(
      gf, 512, WcT, 0, 0, 0, nullptr, nullptr, nullptr, nullptr, nullptr, nullptr, xb, 256);
  // Kt/Vt = (z @ Wkv) transposed per (b,h); 1D grid + XCD swizzle
  k_gemmT<256><<<32 * 128, 256, 0, stream>>>(zb, 256, WkvT, 32, Kt, Vt, 1024, 4);
  // fused instnorm stats + norm + rotary on Kt (in place)
  k_normrot<<<dim3(32, 32), 256, 0, stream>>>(Kt, csT, 2);
  // dotsT[mat] = Vt[mat] * Kt[mat]^T / n
  k_atb2<<<512, 256, 0, stream>>>(Vt, Kt, dotsT, 1.f / 2048.f);
  k_rotq<<<NTOK / 4, 256, 0, stream>>>(xb, qrot, cs);
  // merged[:, h*256:] = qrot @ dotsT[b,h]
  k_gemm<256, E_BF16><<<dim3(4, 128, 4), 256, 0, stream>>>(
      qrot, 256, dotsT, 262144L, 65536L, 256, nullptr, nullptr, nullptr, nullptr, nullptr,
      nullptr, merged, 1024);
  // x2 = merged @ WocaT + boca + x
  k_gemm<1024, E_BIAS_RESB_BOTH><<<dim3(4, 128, 1), 256, 0, stream>>>(
      merged, 1024, WocaT, 0, 0, 0, boca, nullptr, xb, nullptr, nullptr, x2, x2b, 256);
  // t1 = gelu(x2 @ Wf1 + bf1)
  k_gemm<256, E_BIAS_GELU><<<dim3(4, 128, 1), 256, 0, stream>>>(
      x2b, 256, Wf1T, 0, 0, 0, bf1, nullptr, nullptr, nullptr, nullptr, nullptr, t1, 256);
  // x3 = t1 @ Wf2 + bf2 + x2
  k_gemm<256, E_BIAS_RES_F32><<<dim3(4, 128, 1), 256, 0, stream>>>(
      t1, 256, Wf2T, 0, 0, 0, bf2, x2, nullptr, nullptr, nullptr, x3, nullptr, 256);
  k_ln<<<NTOK / 4, 256, 0, stream>>>(x3, lng, lnb, h);
  // p1o = gelu(h @ P1T + pvec*P1L)
  k_gemm<256, E_RANK1_GELU><<<dim3(4, 128, 1), 256, 0, stream>>>(
      h, 256, P1T, 0, 0, 0, nullptr, nullptr, nullptr, P1L, pvec, nullptr, p1o, 256);
  k_gemm<256, E_GELU><<<dim3(4, 128, 1), 256, 0, stream>>>(
      p1o, 256, P2T, 0, 0, 0, nullptr, nullptr, nullptr, nullptr, nullptr, nullptr, p2o, 256);
  // zp = p2o @ P3T + x3
  k_gemm<256, E_RES_BOTH><<<dim3(4, 128, 1), 256, 0, stream>>>(
      p2o, 256, P3T, 0, 0, 0, nullptr, x3, nullptr, nullptr, nullptr, zp, zpb, 256);
  // q2 token-major; k2/v2 transposed
  k_gemm<256, E_BF16><<<dim3(4, 128, 1), 256, 0, stream>>>(
      zpb, 256, WqkvT, 0, 0, 0, nullptr, nullptr, nullptr, nullptr, nullptr, nullptr, q2b, 256);
  k_gemmT<256><<<8 * 128, 256, 0, stream>>>(zpb, 256, WqkvT + 65536, 8, k2t, v2t, 256, 1);
  k_rotq<<<NTOK / 4, 256, 0, stream>>>(q2b, q2b, cs);
  k_normrot<<<dim3(32, 8), 256, 0, stream>>>(k2t, csT, 0);
  k_atb2<<<128, 256, 0, stream>>>(v2t, k2t, dots2T, 1.f / 2048.f);
  // att = q2' @ dots2T[b]
  k_gemm<256, E_BF16><<<dim3(4, 128, 1), 256, 0, stream>>>(
      q2b, 256, dots2T, 65536L, 0, 0, nullptr, nullptr, nullptr, nullptr, nullptr,
      nullptr, att, 256);
  // zd = att @ WodaT + boda + zp
  k_gemm<256, E_BIAS_RES_F32><<<dim3(4, 128, 1), 256, 0, stream>>>(
      att, 256, WodaT, 0, 0, 0, boda, zp, nullptr, nullptr, nullptr, zd, nullptr, 256);
  k_ln<<<NTOK / 4, 256, 0, stream>>>(zd, ln2g, ln2b, h2);
  k_gemm<256, E_GELU><<<dim3(4, 128, 1), 256, 0, stream>>>(
      h2, 256, D1T, 0, 0, 0, nullptr, nullptr, nullptr, nullptr, nullptr, nullptr, g1, 256);
  k_gemm<256, E_GELU><<<dim3(2, 128, 1), 256, 0, stream>>>(
      g1, 256, D2T, 0, 0, 0, nullptr, nullptr, nullptr, nullptr, nullptr, nullptr, g2, 128);
  k_final<<<NTOK / 4, 256, 0, stream>>>(g2, D3, b3, u);
}

// Round 15
// 389.619 us; speedup vs baseline: 1.2322x; 1.0241x over previous
//
#include <hip/hip_runtime.h>
#include <hip/hip_bf16.h>

using bf16 = __hip_bfloat16;
typedef __attribute__((ext_vector_type(8))) short short8;
typedef __attribute__((ext_vector_type(4))) short short4v;
typedef __attribute__((ext_vector_type(4))) float f32x4;

constexpr int BB = 8;
constexpr int NN = 2048;
constexpr int CC = 256;
constexpr int NTOK = BB * NN;  // 16384
constexpr float TWO_PI = 6.283185307179586f;
constexpr float LOG2_1E4 = 13.287712379549449f;

__device__ __forceinline__ float gelu_f(float x) {
  return 0.5f * x * (1.0f + erff(x * 0.7071067811865475f));
}
__device__ __forceinline__ float us2f(unsigned short u) {
  return __uint_as_float(((unsigned)u) << 16);
}
// Bijective XCD-chunk swizzle (requires nwg % 8 == 0).
__device__ __forceinline__ int xcd_swz(int f, int nwg) {
  return (f & 7) * (nwg >> 3) + (f >> 3);
}

template <int T>
__device__ __forceinline__ void stats_rows(const float (*buf)[CC], float* mu, float* rs, float eps) {
  __syncthreads();
  int w = threadIdx.x >> 6, l = threadIdx.x & 63;
  if (w < T) {
    float s = 0.f, s2 = 0.f;
#pragma unroll
    for (int j = 0; j < 4; ++j) { float v = buf[w][l + 64 * j]; s += v; s2 += v * v; }
#pragma unroll
    for (int o = 32; o; o >>= 1) { s += __shfl_down(s, o); s2 += __shfl_down(s2, o); }
    if (l == 0) {
      float m = s * (1.f / 256.f);
      float var = fmaxf(s2 * (1.f / 256.f) - m * m, 0.f);
      mu[w] = m; rs[w] = rsqrtf(var + eps);
    }
  }
  __syncthreads();
}

// ---------------- shared MFMA GEMM core (XOR-swizzled LDS) ------------------
#define GLD16(src, dst)                                                       \
  __builtin_amdgcn_global_load_lds(                                           \
      (const __attribute__((address_space(1))) void*)(src),                   \
      (__attribute__((address_space(3))) void*)(dst), 16, 0, 0)

template <int K, int MI, int NB>
__device__ __forceinline__ void gemm_core(
    const bf16* __restrict__ Ap, int lda, const bf16* __restrict__ Bp,
    bf16 (&As)[NB][MI * 32 * 64], bf16 (&Bs)[NB][64 * 64], f32x4 (&acc)[MI][2]) {
  const int tid = threadIdx.x;
  const int w = tid >> 6, l = tid & 63;
  const int srow = l >> 3;
  const int scol = ((l & 7) ^ srow) * 8;  // swizzled source col
  const int rsw = (l & 7) * 8;            // read-side XOR (row&7 == l&7)
  const int wm = w >> 1, wn = w & 1;

  auto stage_tile = [&](int buf, int kt) {
#pragma unroll
    for (int i = 0; i < MI; ++i) {
      int r = (w * MI + i) * 8 + srow;
      GLD16(Ap + (long)r * lda + kt + scol, &As[buf][(w * MI + i) * 512 + l * 8]);
    }
#pragma unroll
    for (int i = 0; i < 2; ++i) {
      int r = (w * 2 + i) * 8 + srow;
      GLD16(Bp + (long)r * K + kt + scol, &Bs[buf][(w * 2 + i) * 512 + l * 8]);
    }
  };
  auto compute = [&](int buf) {
    short8 bfr[2][2];
#pragma unroll
    for (int ni = 0; ni < 2; ++ni)
#pragma unroll
      for (int ks = 0; ks < 2; ++ks)
        bfr[ni][ks] = *(const short8*)&Bs[buf][(wn * 32 + ni * 16 + (l & 15)) * 64 +
                                               ((ks * 32 + (l >> 4) * 8) ^ rsw)];
#pragma unroll
    for (int mi = 0; mi < MI; ++mi) {
#pragma unroll
      for (int ks = 0; ks < 2; ++ks) {
        short8 afr = *(const short8*)&As[buf][(wm * (MI * 16) + mi * 16 + (l & 15)) * 64 +
                                              ((ks * 32 + (l >> 4) * 8) ^ rsw)];
#pragma unroll
        for (int ni = 0; ni < 2; ++ni)
          acc[mi][ni] = __builtin_amdgcn_mfma_f32_16x16x32_bf16(afr, bfr[ni][ks], acc[mi][ni], 0, 0, 0);
      }
    }
  };

  if constexpr (NB == 2) {
    stage_tile(0, 0);
    asm volatile("s_waitcnt vmcnt(0)" ::: "memory");
    __builtin_amdgcn_s_barrier();
    int cur = 0;
    for (int kt = 0; kt < K; kt += 64) {
      const bool more = (kt + 64 < K);
      if (more) stage_tile(cur ^ 1, kt + 64);
      compute(cur);
      if (more) asm volatile("s_waitcnt vmcnt(0)" ::: "memory");
      __builtin_amdgcn_s_barrier();
      cur ^= 1;
    }
  } else {
    for (int kt = 0; kt < K; kt += 64) {
      stage_tile(0, kt);
      __syncthreads();
      compute(0);
      __syncthreads();
    }
  }
}

// ---------------- k_gemm with fused epilogues (BM=128, BN=64) ---------------
// ozstride: flat element offset added to the OUTPUT per blockIdx.z (for
// per-z output matrices, e.g. the Mw pre-multiply).
enum { E_BF16 = 0, E_BIAS_RESB_BOTH, E_BIAS_GELU, E_BIAS_RES_F32,
       E_RANK1_GELU, E_GELU, E_RES_BOTH };

template <int K, int EPI>
__global__ void __launch_bounds__(256) k_gemm(
    const bf16* __restrict__ A, int lda, const bf16* __restrict__ Bt,
    long bstride, long zstride, int nOffZ, long ozstride,
    const float* __restrict__ bias, const float* __restrict__ res,
    const bf16* __restrict__ resB, const float* __restrict__ rank1,
    const float* __restrict__ pvec,
    float* __restrict__ outF, bf16* __restrict__ outB, int ldo) {
  __shared__ bf16 As[1][128 * 64];
  __shared__ bf16 Bs[1][64 * 64];
  const int tid = threadIdx.x;
  const int w = tid >> 6, l = tid & 63;
  const int m0 = blockIdx.y * 128, n0 = blockIdx.x * 64;
  const int bidx = m0 >> 11;
  const bf16* Bp = Bt + (long)bidx * bstride + (long)blockIdx.z * zstride + (long)n0 * K;
  f32x4 acc[4][2] = {};
  gemm_core<K, 4, 1>(A + (long)m0 * lda, lda, Bp, As, Bs, acc);
  const int wm = w >> 1, wn = w & 1;
  const int zoff = blockIdx.z * nOffZ;
  const long ozoff = (long)blockIdx.z * ozstride;
#pragma unroll
  for (int mi = 0; mi < 4; ++mi) {
#pragma unroll
    for (int ni = 0; ni < 2; ++ni) {
      const int bcol = n0 + wn * 32 + ni * 16 + (l & 15);
      const int ocol = bcol + zoff;
#pragma unroll
      for (int r = 0; r < 4; ++r) {
        const int row = m0 + wm * 64 + mi * 16 + (l >> 4) * 4 + r;
        float v = acc[mi][ni][r];
        const long oidx = (long)row * ldo + ocol + ozoff;
        if constexpr (EPI == E_BF16) { outB[oidx] = __float2bfloat16(v); }
        else if constexpr (EPI == E_BIAS_RESB_BOTH) {
          v += bias[bcol] + __bfloat162float(resB[oidx]);
          outF[oidx] = v; outB[oidx] = __float2bfloat16(v);
        } else if constexpr (EPI == E_BIAS_GELU) {
          v = gelu_f(v + bias[bcol]); outB[oidx] = __float2bfloat16(v);
        } else if constexpr (EPI == E_BIAS_RES_F32) {
          v += bias[bcol] + res[oidx]; outF[oidx] = v;
        } else if constexpr (EPI == E_RANK1_GELU) {
          v = gelu_f(v + pvec[row] * rank1[bcol]); outB[oidx] = __float2bfloat16(v);
        } else if constexpr (EPI == E_GELU) {
          v = gelu_f(v); outB[oidx] = __float2bfloat16(v);
        } else {  // E_RES_BOTH
          v += res[oidx]; outF[oidx] = v; outB[oidx] = __float2bfloat16(v);
        }
      }
    }
  }
}

// ---------------- k_gemmT: GEMM with TRANSPOSED per-matrix output ----------
template <int K>
__global__ void __launch_bounds__(256) k_gemmT(
    const bf16* __restrict__ A, int lda, const bf16* __restrict__ Bt, int nx,
    bf16* __restrict__ T0, bf16* __restrict__ T1, int thresh, int matsPerB) {
  __shared__ union {
    struct { bf16 A[1][128 * 64]; bf16 B[1][64 * 64]; } ab;
    bf16 stage[64 * 132];
  } sm;
  const int tid = threadIdx.x;
  const int w = tid >> 6, l = tid & 63;
  const int f = xcd_swz(blockIdx.x, gridDim.x);
  const int n0 = (f % nx) * 64;
  const int m0 = (f / nx) * 128;
  f32x4 acc[4][2] = {};
  gemm_core<K, 4, 1>(A + (long)m0 * lda, lda, Bt + (long)n0 * K, sm.ab.A, sm.ab.B, acc);
  const int wm = w >> 1, wn = w & 1;
  __syncthreads();
#pragma unroll
  for (int mi = 0; mi < 4; ++mi)
#pragma unroll
    for (int ni = 0; ni < 2; ++ni) {
      int c = wn * 32 + ni * 16 + (l & 15);
      int row0 = wm * 64 + mi * 16 + (l >> 4) * 4;
#pragma unroll
      for (int q = 0; q < 2; ++q) {
        bf16 b0 = __float2bfloat16(acc[mi][ni][2 * q]);
        bf16 b1 = __float2bfloat16(acc[mi][ni][2 * q + 1]);
        unsigned u = (unsigned)*(unsigned short*)&b0 |
                     ((unsigned)*(unsigned short*)&b1 << 16);
        *(unsigned*)&sm.stage[c * 132 + row0 + 2 * q] = u;
      }
    }
  __syncthreads();
  const int b = m0 >> 11, nbase = m0 & 2047;
  const int part = (n0 >= thresh) ? 1 : 0;
  const int cT0 = n0 - (part ? thresh : 0);
  bf16* dst = (part ? T1 : T0) + ((long)(b * matsPerB + (cT0 >> 8))) * 524288
            + (long)(cT0 & 255) * 2048;
  const int c = tid >> 2, ns = tid & 3;
  bf16* rowp = dst + (long)c * 2048 + nbase + ns * 8;
#pragma unroll
  for (int j = 0; j < 4; ++j) {
    short4v lo = *(const short4v*)&sm.stage[c * 132 + ns * 8 + j * 32];
    short4v hi = *(const short4v*)&sm.stage[c * 132 + ns * 8 + j * 32 + 4];
    short8 v;
    v[0] = lo[0]; v[1] = lo[1]; v[2] = lo[2]; v[3] = lo[3];
    v[4] = hi[0]; v[5] = hi[1]; v[6] = hi[2]; v[7] = hi[3];
    *(short8*)&rowp[j * 32] = v;
  }
}

// ---------------- k_atb2: per-mat A[256,2048] @ B[256,2048]^T ---------------
// hconcat=0: D0[mat][row][col] (transposed-dots layout, used by decode).
// hconcat=1: D0[b][col][h*256+row] — dots untransposed, heads concatenated
//            along K so it can be the Bt of the Mw pre-multiply.
__global__ void __launch_bounds__(256) k_atb2(
    const bf16* __restrict__ A0, const bf16* __restrict__ B0,
    bf16* __restrict__ D0, float scale, int hconcat) {
  __shared__ bf16 As[2][2 * 32 * 64];
  __shared__ bf16 Bs[2][64 * 64];
  const int tid = threadIdx.x;
  const int w = tid >> 6, l = tid & 63;
  const int f = xcd_swz(blockIdx.x, gridDim.x);
  const int n0 = (f & 3) * 64;
  const int m0 = ((f >> 2) & 3) * 64;
  const int mat = f >> 4;
  const bf16* Ap = A0 + (long)mat * 524288 + (long)m0 * 2048;
  const bf16* Bp = B0 + (long)mat * 524288 + (long)n0 * 2048;
  f32x4 acc[2][2] = {};
  gemm_core<2048, 2, 2>(Ap, 2048, Bp, As, Bs, acc);
  const int wm = w >> 1, wn = w & 1;
  if (hconcat) {
    const int b = mat >> 2, h = mat & 3;
    bf16* D = D0 + (long)b * 262144 + h * 256;
#pragma unroll
    for (int mi = 0; mi < 2; ++mi)
#pragma unroll
      for (int ni = 0; ni < 2; ++ni) {
        int col = n0 + wn * 32 + ni * 16 + (l & 15);
#pragma unroll
        for (int r = 0; r < 4; ++r) {
          int row = m0 + wm * 32 + mi * 16 + (l >> 4) * 4 + r;
          D[(long)col * 1024 + row] = __float2bfloat16(acc[mi][ni][r] * scale);
        }
      }
  } else {
    bf16* D = D0 + (long)mat * 65536;
#pragma unroll
    for (int mi = 0; mi < 2; ++mi)
#pragma unroll
      for (int ni = 0; ni < 2; ++ni) {
        int col = n0 + wn * 32 + ni * 16 + (l & 15);
#pragma unroll
        for (int r = 0; r < 4; ++r) {
          int row = m0 + wm * 32 + mi * 16 + (l >> 4) * 4 + r;
          D[(long)row * 256 + col] = __float2bfloat16(acc[mi][ni][r] * scale);
        }
      }
  }
}

// ---------------- k_normrot: FUSED stats + norm + rotary on Kt[mat] ---------
__global__ void __launch_bounds__(256) k_normrot(
    bf16* __restrict__ Kt, const bf16* __restrict__ csT, int hshift) {
  __shared__ bf16 tile[256][68];
  __shared__ float ps[4][64], ps2[4][64];
  __shared__ float smu[64], srs[64];
  const int mat = blockIdx.y;
  const int tok0 = blockIdx.x * 64;
  const int b = mat >> hshift;
  const int tid = threadIdx.x;
  bf16* base = Kt + (long)mat * 524288 + tok0;
  const int cr = tid >> 3;
  const int cj = (tid & 7) * 8;
#pragma unroll
  for (int g = 0; g < 8; ++g) {
    int c = g * 32 + cr;
    *(short8*)&tile[c][cj] = *(const short8*)&base[(long)c * 2048 + cj];
  }
  __syncthreads();
  {
    const int tk = tid & 63, q = tid >> 6;
    float s = 0.f, s2 = 0.f;
#pragma unroll 8
    for (int cc = 0; cc < 64; ++cc) {
      float v = us2f(*(const unsigned short*)&tile[q * 64 + cc][tk]);
      s += v; s2 += v * v;
    }
    ps[q][tk] = s; ps2[q][tk] = s2;
  }
  __syncthreads();
  if (tid < 64) {
    float s = ps[0][tid] + ps[1][tid] + ps[2][tid] + ps[3][tid];
    float s2 = ps2[0][tid] + ps2[1][tid] + ps2[2][tid] + ps2[3][tid];
    float m = s * (1.f / 256.f);
    smu[tid] = m;
    srs[tid] = rsqrtf(fmaxf(s2 * (1.f / 256.f) - m * m, 0.f) + 1e-5f);
  }
  __syncthreads();
  const long ctok = (long)b * 2048 + tok0 + cj;
#pragma unroll
  for (int g = 0; g < 4; ++g) {
    int c = g * 32 + cr;
    short8 v0 = *(const short8*)&tile[c][cj];
    short8 v1 = *(const short8*)&tile[c + 128][cj];
    const bf16* cop = csT + (long)(c * 2) * 16384 + ctok;
    short8 co8 = *(const short8*)cop;
    short8 si8 = *(const short8*)(cop + 16384);
    short8 o0, o1;
#pragma unroll
    for (int e = 0; e < 8; ++e) {
      float m = smu[cj + e], r = srs[cj + e];
      float a = (us2f((unsigned short)v0[e]) - m) * r;
      float bb = (us2f((unsigned short)v1[e]) - m) * r;
      float co = us2f((unsigned short)co8[e]);
      float si = us2f((unsigned short)si8[e]);
      bf16 t0 = __float2bfloat16(a * co - bb * si);
      bf16 t1 = __float2bfloat16(bb * co + a * si);
      o0[e] = *(short*)&t0; o1[e] = *(short*)&t1;
    }
    *(short8*)&base[(long)c * 2048 + cj] = o0;
    *(short8*)&base[(long)(c + 128) * 2048 + cj] = o1;
  }
}

// token-major instnorm + rotary (4 tokens/block); in may equal out
__global__ void __launch_bounds__(256) k_rotq(
    const bf16* __restrict__ in, bf16* __restrict__ out, const bf16* __restrict__ cs) {
  __shared__ float xr[4][CC];
  __shared__ float mu[4], rs[4];
  int tid = threadIdx.x;
  long tok0 = (long)blockIdx.x * 4;
#pragma unroll
  for (int t = 0; t < 4; ++t) xr[t][tid] = __bfloat162float(in[(tok0 + t) * 256 + tid]);
  stats_rows<4>(xr, mu, rs, 1e-5f);
  int i = tid & 127;
#pragma unroll
  for (int t = 0; t < 4; ++t) {
    float co = __bfloat162float(cs[(tok0 + t) * 256 + i]);
    float si = __bfloat162float(cs[(tok0 + t) * 256 + 128 + i]);
    float n0 = (xr[t][tid] - mu[t]) * rs[t];
    float n1 = (xr[t][tid ^ 128] - mu[t]) * rs[t];
    float o = (tid < 128) ? (n0 * co - n1 * si) : (n0 * co + n1 * si);
    out[(tok0 + t) * 256 + tid] = __float2bfloat16(o);
  }
}

// ---------------- weight prep: 12 transposes, one kernel --------------------
struct WEnt { const float* s; bf16* d; int K; int N; int blk0; };
struct WTab { WEnt e[12]; };

__global__ void __launch_bounds__(256) k_wprep(WTab t) {
  int bid = blockIdx.x;
  int ei = 0;
#pragma unroll
  for (int i = 1; i < 12; ++i)
    if (bid >= t.e[i].blk0) ei = i;
  WEnt e = t.e[ei];
  int local = (bid - e.blk0) * 256 + threadIdx.x;
  if (local < e.K * e.N) {
    int n = local / e.K, k = local - n * e.K;
    e.d[local] = __float2bfloat16(e.s[(long)k * e.N + n]);
  }
}

// ---------------- k_csT: transposed cos/sin table, coalesced writes ---------
__global__ void __launch_bounds__(256) k_csT(
    const float* __restrict__ pos, bf16* __restrict__ csT) {
  const int c = blockIdx.y;
  const int n = blockIdx.x * 256 + threadIdx.x;
  float inv = exp2f(-((float)c * (1.f / 128.f)) * LOG2_1E4);
  float fh = pos[n] * 2048.f * inv;
  float s, co; sincosf(fh, &s, &co);
  csT[(long)(c * 2) * 16384 + n] = __float2bfloat16(co);
  csT[(long)(c * 2 + 1) * 16384 + n] = __float2bfloat16(s);
}

// ---------------- k_pre: fourier feats, token-major cos/sin, pvec, z->bf16 --
__global__ void __launch_bounds__(256) k_pre(
    const float* __restrict__ pos, const float* __restrict__ Bf,
    const float* __restrict__ z, const float* __restrict__ P1,
    bf16* __restrict__ gf, bf16* __restrict__ cs,
    float* __restrict__ pvec, bf16* __restrict__ zb, float* __restrict__ P1L) {
  int tid = threadIdx.x;
  long tok0 = (long)blockIdx.x * 4;
  if (blockIdx.x == 0) P1L[tid] = P1[65536 + tid];
  float p[4];
#pragma unroll
  for (int t = 0; t < 4; ++t) p[t] = pos[tok0 + t];
  if (tid < 4) pvec[tok0 + tid] = p[tid] * 0.0625f;
  float bfc = Bf[tid];
#pragma unroll
  for (int t = 0; t < 4; ++t) {
    float xp = TWO_PI * (p[t] * 0.0625f) * bfc;
    float s, c; sincosf(xp, &s, &c);
    gf[(tok0 + t) * 512 + tid] = __float2bfloat16(gelu_f(s));
    gf[(tok0 + t) * 512 + 256 + tid] = __float2bfloat16(gelu_f(c));
    zb[(tok0 + t) * 256 + tid] = __float2bfloat16(z[(tok0 + t) * 256 + tid]);
  }
  if (tid < 128) {
    float inv = exp2f(-((float)tid * (1.f / 128.f)) * LOG2_1E4);
#pragma unroll
    for (int t = 0; t < 4; ++t) {
      float fh = p[t] * 2048.f * inv;
      float s, c; sincosf(fh, &s, &c);
      cs[(tok0 + t) * 256 + tid] = __float2bfloat16(c);
      cs[(tok0 + t) * 256 + 128 + tid] = __float2bfloat16(s);
    }
  }
}

__global__ void __launch_bounds__(256) k_ln(
    const float* __restrict__ xin, const float* __restrict__ g,
    const float* __restrict__ b, bf16* __restrict__ hout) {
  __shared__ float xr[4][CC];
  __shared__ float mu[4], rs[4];
  int tid = threadIdx.x;
  long tok0 = (long)blockIdx.x * 4;
#pragma unroll
  for (int t = 0; t < 4; ++t) xr[t][tid] = xin[(tok0 + t) * 256 + tid];
  stats_rows<4>(xr, mu, rs, 1e-5f);
  float gv = g[tid], bv = b[tid];
#pragma unroll
  for (int t = 0; t < 4; ++t)
    hout[(tok0 + t) * 256 + tid] = __float2bfloat16((xr[t][tid] - mu[t]) * rs[t] * gv + bv);
}

__global__ void __launch_bounds__(256) k_final(
    const bf16* __restrict__ g2, const float* __restrict__ D3,
    const float* __restrict__ b3, float* __restrict__ u) {
  int w = threadIdx.x >> 6, l = threadIdx.x & 63;
  long tok = (long)blockIdx.x * 4 + w;
  float s = __bfloat162float(g2[tok * 128 + l]) * D3[l]
          + __bfloat162float(g2[tok * 128 + 64 + l]) * D3[64 + l];
#pragma unroll
  for (int o = 32; o; o >>= 1) s += __shfl_down(s, o);
  if (l == 0) u[tok] = s + b3[0];
}

// ======================= launcher ===========================================
extern "C" void kernel_launch(void* const* d_in, const int* in_sizes, int n_in,
                              void* d_out, int out_size, void* d_ws, size_t ws_size,
                              hipStream_t stream) {
  const float* z    = (const float*)d_in[0];
  const float* pos  = (const float*)d_in[1];
  const float* Bf   = (const float*)d_in[2];
  const float* Wc   = (const float*)d_in[3];
  const float* Wkv  = (const float*)d_in[4];
  const float* Woca = (const float*)d_in[5];
  const float* boca = (const float*)d_in[6];
  const float* Wf1  = (const float*)d_in[7];
  const float* bf1  = (const float*)d_in[8];
  const float* Wf2  = (const float*)d_in[9];
  const float* bf2  = (const float*)d_in[10];
  const float* lng  = (const float*)d_in[11];
  const float* lnb  = (const float*)d_in[12];
  const float* P1   = (const float*)d_in[13];
  const float* P2   = (const float*)d_in[14];
  const float* P3   = (const float*)d_in[15];
  const float* Wqkv = (const float*)d_in[16];
  const float* Woda = (const float*)d_in[17];
  const float* boda = (const float*)d_in[18];
  const float* ln2g = (const float*)d_in[19];
  const float* ln2b = (const float*)d_in[20];
  const float* D1   = (const float*)d_in[21];
  const float* D2   = (const float*)d_in[22];
  const float* D3   = (const float*)d_in[23];
  const float* b3   = (const float*)d_in[24];

  float* u  = (float*)d_out;
  float* zp = (float*)d_out + NTOK;

  const long MB = 1048576L;
  char* ws = (char*)d_ws;
  // ---- static region [0, 24MB) ----
  bf16*  cs   = (bf16*)(ws);
  bf16*  csT  = (bf16*)(ws + 8 * MB);
  float* pvec = (float*)(ws + 16 * MB);
  long wo = 16 * MB + 65536;
  bf16* WcT   = (bf16*)(ws + wo);               wo += 262144;
  bf16* WkvT  = (bf16*)(ws + wo);               wo += 1048576;
  bf16* WocaT = (bf16*)(ws + wo);               wo += 524288;
  bf16* Wf1T  = (bf16*)(ws + wo);               wo += 131072;
  bf16* Wf2T  = (bf16*)(ws + wo);               wo += 131072;
  bf16* P1T   = (bf16*)(ws + wo);               wo += 131072;
  bf16* P2T   = (bf16*)(ws + wo);               wo += 131072;
  bf16* P3T   = (bf16*)(ws + wo);               wo += 131072;
  bf16* WqkvT = (bf16*)(ws + wo);               wo += 393216;
  bf16* WodaT = (bf16*)(ws + wo);               wo += 131072;
  bf16* D1T   = (bf16*)(ws + wo);               wo += 131072;
  bf16* D2T   = (bf16*)(ws + wo);               wo += 65536;
  float* P1L  = (float*)(ws + wo);              wo += 1024;
  // ---- dynamic arena at 24 MB (lifetime-audited; overlaps only across
  //      sequential launches) ----
  char* AR = ws + 24 * MB;
  bf16*  xb     = (bf16*)(AR);             // [0,8)   W4  R9'(x2 residual)
  bf16*  zb     = (bf16*)(AR + 8 * MB);    // [8,16)  W2  R5
  bf16*  gf     = (bf16*)(AR + 48 * MB);   // [48,64) W2  R4 (Vt W5 after)
  bf16*  Kt     = (bf16*)(AR + 16 * MB);   // [16,48) W5/6 R7
  bf16*  Vt     = (bf16*)(AR + 48 * MB);   // [48,80) W5  R7
  bf16*  dotsH  = (bf16*)(AR + 8 * MB);    // [8,12)  W7  R8b (zb R5 done)
  bf16*  MwT    = (bf16*)(AR + 12 * MB);   // [12,13) W8b R9'
  bf16*  qrot   = (bf16*)(AR + 16 * MB);   // [16,24) W8  R9' (Kt R7 done)
  float* x2     = (float*)(AR + 56 * MB);  // [56,72) W9' R11 (f32; Vt R7 done)
  bf16*  x2b    = (bf16*)(AR + 72 * MB);   // [72,80) W9' R10
  bf16*  t1     = (bf16*)(AR + 24 * MB);   // [24,32) W10 R11
  float* x3     = (float*)(AR + 32 * MB);  // [32,48) W11 R15 (f32)
  bf16*  h      = (bf16*)(AR + 16 * MB);   // [16,24) W12 R13 (qrot R9' done)
  bf16*  p1o    = (bf16*)(AR + 24 * MB);   // [24,32) W13 R14 (t1 R11 done)
  bf16*  p2o    = (bf16*)(AR + 48 * MB);   // [48,56) W14 R15 (Vt R7 done)
  bf16*  zpb    = (bf16*)(AR + 56 * MB);   // [56,64) W15 R17 (x2 R11 done)
  bf16*  q2b    = (bf16*)(AR + 64 * MB);   // [64,72) W16/18 R21
  bf16*  k2t    = (bf16*)(AR + 72 * MB);   // [72,80) W17/19 R20 (x2b R10 done)
  bf16*  v2t    = (bf16*)(AR + 8 * MB);    // [8,16)  W17 R20 (dotsH/MwT done)
  bf16*  dots2T = (bf16*)(AR + 16 * MB);   // [16,17) W20 R21 (h R13 done)
  bf16*  att    = (bf16*)(AR + 24 * MB);   // [24,32) W21 R22 (p1o R14 done)
  float* zd     = (float*)(AR + 32 * MB);  // [32,48) W22 R23 (x3 R15 done)
  bf16*  h2     = (bf16*)(AR + 8 * MB);    // [8,16)  W23 R24 (v2t R20 done)
  bf16*  g1     = (bf16*)(AR + 16 * MB);   // [16,24) W24 R25
  bf16*  g2     = (bf16*)(AR + 24 * MB);   // [24,28) W25 R26

  // ---- weight-prep table ----
  WTab tab;
  int nb = 0;
  auto add = [&](int i, const float* s, bf16* d, int K_, int N_) {
    tab.e[i].s = s; tab.e[i].d = d; tab.e[i].K = K_; tab.e[i].N = N_;
    tab.e[i].blk0 = nb; nb += (K_ * N_) / 256;
  };
  add(0, Wc, WcT, 512, 256);
  add(1, Wkv, WkvT, 256, 2048);
  add(2, Woca, WocaT, 1024, 256);
  add(3, Wf1, Wf1T, 256, 256);
  add(4, Wf2, Wf2T, 256, 256);
  add(5, P1, P1T, 256, 256);
  add(6, P2, P2T, 256, 256);
  add(7, P3, P3T, 256, 256);
  add(8, Wqkv, WqkvT, 256, 768);
  add(9, Woda, WodaT, 256, 256);
  add(10, D1, D1T, 256, 256);
  add(11, D2, D2T, 256, 128);
  k_wprep<<<nb, 256, 0, stream>>>(tab);                                       // 1

  k_pre<<<NTOK / 4, 256, 0, stream>>>(pos, Bf, z, P1, gf, cs, pvec, zb, P1L); // 2
  k_csT<<<dim3(NTOK / 256, 128), 256, 0, stream>>>(pos, csT);                 // 3
  // 4: x = gelu(fourier) @ WcT
  k_gemm<512, E_BF16><<<dim3(4, 128, 1), 256, 0, stream>>>(
      gf, 512, WcT, 0, 0, 0, 0, nullptr, nullptr, nullptr, nullptr, nullptr,
      nullptr, xb, 256);
  // 5: Kt/Vt = (z @ Wkv) transposed per (b,h)
  k_gemmT<256><<<32 * 128, 256, 0, stream>>>(zb, 256, WkvT, 32, Kt, Vt, 1024, 4);
  // 6: fused instnorm + rotary on Kt (in place)
  k_normrot<<<dim3(32, 32), 256, 0, stream>>>(Kt, csT, 2);
  // 7: dotsH[b][d][h*256+e] = (Vt*Kt^T/n) untransposed, H-concat along K
  k_atb2<<<512, 256, 0, stream>>>(Vt, Kt, dotsH, 1.f / 2048.f, 1);
  // 8: qrot
  k_rotq<<<NTOK / 4, 256, 0, stream>>>(xb, qrot, cs);
  // 8b: MwT[b] = WocaT @ dotsH[b]  (head-sum pre-multiply: q is head-invariant)
  k_gemm<1024, E_BF16><<<dim3(4, 2, 8), 256, 0, stream>>>(
      WocaT, 1024, dotsH, 0, 262144L, 0, 65536L, nullptr, nullptr, nullptr,
      nullptr, nullptr, nullptr, MwT, 256);
  // 9': x2 = qrot @ MwT[b] + boca + x   (replaces merged + Woca GEMMs)
  k_gemm<256, E_BIAS_RESB_BOTH><<<dim3(4, 128, 1), 256, 0, stream>>>(
      qrot, 256, MwT, 65536L, 0, 0, 0, boca, nullptr, xb, nullptr, nullptr,
      x2, x2b, 256);
  // 10: t1 = gelu(x2 @ Wf1 + bf1)
  k_gemm<256, E_BIAS_GELU><<<dim3(4, 128, 1), 256, 0, stream>>>(
      x2b, 256, Wf1T, 0, 0, 0, 0, bf1, nullptr, nullptr, nullptr, nullptr,
      nullptr, t1, 256);
  // 11: x3 = t1 @ Wf2 + bf2 + x2
  k_gemm<256, E_BIAS_RES_F32><<<dim3(4, 128, 1), 256, 0, stream>>>(
      t1, 256, Wf2T, 0, 0, 0, 0, bf2, x2, nullptr, nullptr, nullptr,
      x3, nullptr, 256);
  k_ln<<<NTOK / 4, 256, 0, stream>>>(x3, lng, lnb, h);                        // 12
  // 13: p1o = gelu(h @ P1T + pvec*P1L)
  k_gemm<256, E_RANK1_GELU><<<dim3(4, 128, 1), 256, 0, stream>>>(
      h, 256, P1T, 0, 0, 0, 0, nullptr, nullptr, nullptr, P1L, pvec,
      nullptr, p1o, 256);
  // 14
  k_gemm<256, E_GELU><<<dim3(4, 128, 1), 256, 0, stream>>>(
      p1o, 256, P2T, 0, 0, 0, 0, nullptr, nullptr, nullptr, nullptr, nullptr,
      nullptr, p2o, 256);
  // 15: zp = p2o @ P3T + x3
  k_gemm<256, E_RES_BOTH><<<dim3(4, 128, 1), 256, 0, stream>>>(
      p2o, 256, P3T, 0, 0, 0, 0, nullptr, x3, nullptr, nullptr, nullptr,
      zp, zpb, 256);
  // 16: q2 token-major
  k_gemm<256, E_BF16><<<dim3(4, 128, 1), 256, 0, stream>>>(
      zpb, 256, WqkvT, 0, 0, 0, 0, nullptr, nullptr, nullptr, nullptr, nullptr,
      nullptr, q2b, 256);
  // 17: k2/v2 transposed
  k_gemmT<256><<<8 * 128, 256, 0, stream>>>(zpb, 256, WqkvT + 65536, 8, k2t, v2t, 256, 1);
  k_rotq<<<NTOK / 4, 256, 0, stream>>>(q2b, q2b, cs);                         // 18
  k_normrot<<<dim3(32, 8), 256, 0, stream>>>(k2t, csT, 0);                    // 19
  k_atb2<<<128, 256, 0, stream>>>(v2t, k2t, dots2T, 1.f / 2048.f, 0);         // 20
  // 21: att = q2' @ dots2T[b]
  k_gemm<256, E_BF16><<<dim3(4, 128, 1), 256, 0, stream>>>(
      q2b, 256, dots2T, 65536L, 0, 0, 0, nullptr, nullptr, nullptr, nullptr,
      nullptr, nullptr, att, 256);
  // 22: zd = att @ WodaT + boda + zp
  k_gemm<256, E_BIAS_RES_F32><<<dim3(4, 128, 1), 256, 0, stream>>>(
      att, 256, WodaT, 0, 0, 0, 0, boda, zp, nullptr, nullptr, nullptr,
      zd, nullptr, 256);
  k_ln<<<NTOK / 4, 256, 0, stream>>>(zd, ln2g, ln2b, h2);                     // 23
  // 24
  k_gemm<256, E_GELU><<<dim3(4, 128, 1), 256, 0, stream>>>(
      h2, 256, D1T, 0, 0, 0, 0, nullptr, nullptr, nullptr, nullptr, nullptr,
      nullptr, g1, 256);
  // 25
  k_gemm<256, E_GELU><<<dim3(2, 128, 1), 256, 0, stream>>>(
      g1, 256, D2T, 0, 0, 0, 0, nullptr, nullptr, nullptr, nullptr, nullptr,
      nullptr, g2, 128);
  k_final<<<NTOK / 4, 256, 0, stream>>>(g2, D3, b3, u);                       // 26
}

// Round 16
// 387.010 us; speedup vs baseline: 1.2405x; 1.0067x over previous
//
#include <hip/hip_runtime.h>
#include <hip/hip_bf16.h>

using bf16 = __hip_bfloat16;
typedef __attribute__((ext_vector_type(8))) short short8;
typedef __attribute__((ext_vector_type(4))) short short4v;
typedef __attribute__((ext_vector_type(4))) float f32x4;

constexpr int BB = 8;
constexpr int NN = 2048;
constexpr int CC = 256;
constexpr int NTOK = BB * NN;  // 16384
constexpr float TWO_PI = 6.283185307179586f;
constexpr float LOG2_1E4 = 13.287712379549449f;

__device__ __forceinline__ float gelu_f(float x) {
  return 0.5f * x * (1.0f + erff(x * 0.7071067811865475f));
}
__device__ __forceinline__ float us2f(unsigned short u) {
  return __uint_as_float(((unsigned)u) << 16);
}
// Bijective XCD-chunk swizzle (requires nwg % 8 == 0).
__device__ __forceinline__ int xcd_swz(int f, int nwg) {
  return (f & 7) * (nwg >> 3) + (f >> 3);
}

template <int T>
__device__ __forceinline__ void stats_rows(const float (*buf)[CC], float* mu, float* rs, float eps) {
  __syncthreads();
  int w = threadIdx.x >> 6, l = threadIdx.x & 63;
  if (w < T) {
    float s = 0.f, s2 = 0.f;
#pragma unroll
    for (int j = 0; j < 4; ++j) { float v = buf[w][l + 64 * j]; s += v; s2 += v * v; }
#pragma unroll
    for (int o = 32; o; o >>= 1) { s += __shfl_down(s, o); s2 += __shfl_down(s2, o); }
    if (l == 0) {
      float m = s * (1.f / 256.f);
      float var = fmaxf(s2 * (1.f / 256.f) - m * m, 0.f);
      mu[w] = m; rs[w] = rsqrtf(var + eps);
    }
  }
  __syncthreads();
}

// ---------------- shared MFMA GEMM core (XOR-swizzled LDS) ------------------
#define GLD16(src, dst)                                                       \
  __builtin_amdgcn_global_load_lds(                                           \
      (const __attribute__((address_space(1))) void*)(src),                   \
      (__attribute__((address_space(3))) void*)(dst), 16, 0, 0)

template <int K, int MI, int NB>
__device__ __forceinline__ void gemm_core(
    const bf16* __restrict__ Ap, int lda, const bf16* __restrict__ Bp,
    bf16 (&As)[NB][MI * 32 * 64], bf16 (&Bs)[NB][64 * 64], f32x4 (&acc)[MI][2]) {
  const int tid = threadIdx.x;
  const int w = tid >> 6, l = tid & 63;
  const int srow = l >> 3;
  const int scol = ((l & 7) ^ srow) * 8;  // swizzled source col
  const int rsw = (l & 7) * 8;            // read-side XOR (row&7 == l&7)
  const int wm = w >> 1, wn = w & 1;

  auto stage_tile = [&](int buf, int kt) {
#pragma unroll
    for (int i = 0; i < MI; ++i) {
      int r = (w * MI + i) * 8 + srow;
      GLD16(Ap + (long)r * lda + kt + scol, &As[buf][(w * MI + i) * 512 + l * 8]);
    }
#pragma unroll
    for (int i = 0; i < 2; ++i) {
      int r = (w * 2 + i) * 8 + srow;
      GLD16(Bp + (long)r * K + kt + scol, &Bs[buf][(w * 2 + i) * 512 + l * 8]);
    }
  };
  auto compute = [&](int buf) {
    short8 bfr[2][2];
#pragma unroll
    for (int ni = 0; ni < 2; ++ni)
#pragma unroll
      for (int ks = 0; ks < 2; ++ks)
        bfr[ni][ks] = *(const short8*)&Bs[buf][(wn * 32 + ni * 16 + (l & 15)) * 64 +
                                               ((ks * 32 + (l >> 4) * 8) ^ rsw)];
#pragma unroll
    for (int mi = 0; mi < MI; ++mi) {
#pragma unroll
      for (int ks = 0; ks < 2; ++ks) {
        short8 afr = *(const short8*)&As[buf][(wm * (MI * 16) + mi * 16 + (l & 15)) * 64 +
                                              ((ks * 32 + (l >> 4) * 8) ^ rsw)];
#pragma unroll
        for (int ni = 0; ni < 2; ++ni)
          acc[mi][ni] = __builtin_amdgcn_mfma_f32_16x16x32_bf16(afr, bfr[ni][ks], acc[mi][ni], 0, 0, 0);
      }
    }
  };

  if constexpr (NB == 2) {
    stage_tile(0, 0);
    asm volatile("s_waitcnt vmcnt(0)" ::: "memory");
    __builtin_amdgcn_s_barrier();
    int cur = 0;
    for (int kt = 0; kt < K; kt += 64) {
      const bool more = (kt + 64 < K);
      if (more) stage_tile(cur ^ 1, kt + 64);
      compute(cur);
      if (more) asm volatile("s_waitcnt vmcnt(0)" ::: "memory");
      __builtin_amdgcn_s_barrier();
      cur ^= 1;
    }
  } else {
    for (int kt = 0; kt < K; kt += 64) {
      stage_tile(0, kt);
      __syncthreads();
      compute(0);
      __syncthreads();
    }
  }
}

// ---------------- k_gemm with fused epilogues (BM=128, BN=64) ---------------
enum { E_BF16 = 0, E_BIAS_RESB_BF16, E_BIAS_GELU, E_BIAS_RESB_F32,
       E_RANK1_GELU, E_GELU, E_RES_BOTH };

template <int K, int EPI>
__global__ void __launch_bounds__(256) k_gemm(
    const bf16* __restrict__ A, int lda, const bf16* __restrict__ Bt,
    long bstride, long zstride, int nOffZ, long ozstride,
    const float* __restrict__ bias, const float* __restrict__ res,
    const bf16* __restrict__ resB, const float* __restrict__ rank1,
    const float* __restrict__ pvec,
    float* __restrict__ outF, bf16* __restrict__ outB, int ldo) {
  __shared__ bf16 As[1][128 * 64];
  __shared__ bf16 Bs[1][64 * 64];
  const int tid = threadIdx.x;
  const int w = tid >> 6, l = tid & 63;
  const int m0 = blockIdx.y * 128, n0 = blockIdx.x * 64;
  const int bidx = m0 >> 11;
  const bf16* Bp = Bt + (long)bidx * bstride + (long)blockIdx.z * zstride + (long)n0 * K;
  f32x4 acc[4][2] = {};
  gemm_core<K, 4, 1>(A + (long)m0 * lda, lda, Bp, As, Bs, acc);
  const int wm = w >> 1, wn = w & 1;
  const int zoff = blockIdx.z * nOffZ;
  const long ozoff = (long)blockIdx.z * ozstride;
#pragma unroll
  for (int mi = 0; mi < 4; ++mi) {
#pragma unroll
    for (int ni = 0; ni < 2; ++ni) {
      const int bcol = n0 + wn * 32 + ni * 16 + (l & 15);
      const int ocol = bcol + zoff;
#pragma unroll
      for (int r = 0; r < 4; ++r) {
        const int row = m0 + wm * 64 + mi * 16 + (l >> 4) * 4 + r;
        float v = acc[mi][ni][r];
        const long oidx = (long)row * ldo + ocol + ozoff;
        if constexpr (EPI == E_BF16) { outB[oidx] = __float2bfloat16(v); }
        else if constexpr (EPI == E_BIAS_RESB_BF16) {
          v += bias[bcol] + __bfloat162float(resB[oidx]);
          outB[oidx] = __float2bfloat16(v);
        } else if constexpr (EPI == E_BIAS_GELU) {
          v = gelu_f(v + bias[bcol]); outB[oidx] = __float2bfloat16(v);
        } else if constexpr (EPI == E_BIAS_RESB_F32) {
          v += bias[bcol] + __bfloat162float(resB[oidx]);
          outF[oidx] = v;
        } else if constexpr (EPI == E_RANK1_GELU) {
          v = gelu_f(v + pvec[row] * rank1[bcol]); outB[oidx] = __float2bfloat16(v);
        } else if constexpr (EPI == E_GELU) {
          v = gelu_f(v); outB[oidx] = __float2bfloat16(v);
        } else {  // E_RES_BOTH (f32 res)
          v += res[oidx]; outF[oidx] = v; outB[oidx] = __float2bfloat16(v);
        }
      }
    }
  }
}

// ---------------- k_gemmT: GEMM with TRANSPOSED per-matrix output ----------
template <int K>
__global__ void __launch_bounds__(256) k_gemmT(
    const bf16* __restrict__ A, int lda, const bf16* __restrict__ Bt, int nx,
    bf16* __restrict__ T0, bf16* __restrict__ T1, int thresh, int matsPerB) {
  __shared__ union {
    struct { bf16 A[1][128 * 64]; bf16 B[1][64 * 64]; } ab;
    bf16 stage[64 * 132];
  } sm;
  const int tid = threadIdx.x;
  const int w = tid >> 6, l = tid & 63;
  const int f = xcd_swz(blockIdx.x, gridDim.x);
  const int n0 = (f % nx) * 64;
  const int m0 = (f / nx) * 128;
  f32x4 acc[4][2] = {};
  gemm_core<K, 4, 1>(A + (long)m0 * lda, lda, Bt + (long)n0 * K, sm.ab.A, sm.ab.B, acc);
  const int wm = w >> 1, wn = w & 1;
  __syncthreads();
#pragma unroll
  for (int mi = 0; mi < 4; ++mi)
#pragma unroll
    for (int ni = 0; ni < 2; ++ni) {
      int c = wn * 32 + ni * 16 + (l & 15);
      int row0 = wm * 64 + mi * 16 + (l >> 4) * 4;
#pragma unroll
      for (int q = 0; q < 2; ++q) {
        bf16 b0 = __float2bfloat16(acc[mi][ni][2 * q]);
        bf16 b1 = __float2bfloat16(acc[mi][ni][2 * q + 1]);
        unsigned u = (unsigned)*(unsigned short*)&b0 |
                     ((unsigned)*(unsigned short*)&b1 << 16);
        *(unsigned*)&sm.stage[c * 132 + row0 + 2 * q] = u;
      }
    }
  __syncthreads();
  const int b = m0 >> 11, nbase = m0 & 2047;
  const int part = (n0 >= thresh) ? 1 : 0;
  const int cT0 = n0 - (part ? thresh : 0);
  bf16* dst = (part ? T1 : T0) + ((long)(b * matsPerB + (cT0 >> 8))) * 524288
            + (long)(cT0 & 255) * 2048;
  const int c = tid >> 2, ns = tid & 3;
  bf16* rowp = dst + (long)c * 2048 + nbase + ns * 8;
#pragma unroll
  for (int j = 0; j < 4; ++j) {
    short4v lo = *(const short4v*)&sm.stage[c * 132 + ns * 8 + j * 32];
    short4v hi = *(const short4v*)&sm.stage[c * 132 + ns * 8 + j * 32 + 4];
    short8 v;
    v[0] = lo[0]; v[1] = lo[1]; v[2] = lo[2]; v[3] = lo[3];
    v[4] = hi[0]; v[5] = hi[1]; v[6] = hi[2]; v[7] = hi[3];
    *(short8*)&rowp[j * 32] = v;
  }
}

// ---------------- k_atb2: per-mat A[256,2048] @ B[256,2048]^T ---------------
// hconcat=0: D0[mat][row][col]. hconcat=1: D0[b][col][h*256+row].
__global__ void __launch_bounds__(256) k_atb2(
    const bf16* __restrict__ A0, const bf16* __restrict__ B0,
    bf16* __restrict__ D0, float scale, int hconcat) {
  __shared__ bf16 As[2][2 * 32 * 64];
  __shared__ bf16 Bs[2][64 * 64];
  const int tid = threadIdx.x;
  const int w = tid >> 6, l = tid & 63;
  const int f = xcd_swz(blockIdx.x, gridDim.x);
  const int n0 = (f & 3) * 64;
  const int m0 = ((f >> 2) & 3) * 64;
  const int mat = f >> 4;
  const bf16* Ap = A0 + (long)mat * 524288 + (long)m0 * 2048;
  const bf16* Bp = B0 + (long)mat * 524288 + (long)n0 * 2048;
  f32x4 acc[2][2] = {};
  gemm_core<2048, 2, 2>(Ap, 2048, Bp, As, Bs, acc);
  const int wm = w >> 1, wn = w & 1;
  if (hconcat) {
    const int b = mat >> 2, h = mat & 3;
    bf16* D = D0 + (long)b * 262144 + h * 256;
#pragma unroll
    for (int mi = 0; mi < 2; ++mi)
#pragma unroll
      for (int ni = 0; ni < 2; ++ni) {
        int col = n0 + wn * 32 + ni * 16 + (l & 15);
#pragma unroll
        for (int r = 0; r < 4; ++r) {
          int row = m0 + wm * 32 + mi * 16 + (l >> 4) * 4 + r;
          D[(long)col * 1024 + row] = __float2bfloat16(acc[mi][ni][r] * scale);
        }
      }
  } else {
    bf16* D = D0 + (long)mat * 65536;
#pragma unroll
    for (int mi = 0; mi < 2; ++mi)
#pragma unroll
      for (int ni = 0; ni < 2; ++ni) {
        int col = n0 + wn * 32 + ni * 16 + (l & 15);
#pragma unroll
        for (int r = 0; r < 4; ++r) {
          int row = m0 + wm * 32 + mi * 16 + (l >> 4) * 4 + r;
          D[(long)row * 256 + col] = __float2bfloat16(acc[mi][ni][r] * scale);
        }
      }
  }
}

// ---------------- k_normrot: FUSED stats + norm + rotary on Kt[mat] ---------
__global__ void __launch_bounds__(256) k_normrot(
    bf16* __restrict__ Kt, const bf16* __restrict__ csT, int hshift) {
  __shared__ bf16 tile[256][68];
  __shared__ float ps[4][64], ps2[4][64];
  __shared__ float smu[64], srs[64];
  const int mat = blockIdx.y;
  const int tok0 = blockIdx.x * 64;
  const int b = mat >> hshift;
  const int tid = threadIdx.x;
  bf16* base = Kt + (long)mat * 524288 + tok0;
  const int cr = tid >> 3;
  const int cj = (tid & 7) * 8;
#pragma unroll
  for (int g = 0; g < 8; ++g) {
    int c = g * 32 + cr;
    *(short8*)&tile[c][cj] = *(const short8*)&base[(long)c * 2048 + cj];
  }
  __syncthreads();
  {
    const int tk = tid & 63, q = tid >> 6;
    float s = 0.f, s2 = 0.f;
#pragma unroll 8
    for (int cc = 0; cc < 64; ++cc) {
      float v = us2f(*(const unsigned short*)&tile[q * 64 + cc][tk]);
      s += v; s2 += v * v;
    }
    ps[q][tk] = s; ps2[q][tk] = s2;
  }
  __syncthreads();
  if (tid < 64) {
    float s = ps[0][tid] + ps[1][tid] + ps[2][tid] + ps[3][tid];
    float s2 = ps2[0][tid] + ps2[1][tid] + ps2[2][tid] + ps2[3][tid];
    float m = s * (1.f / 256.f);
    smu[tid] = m;
    srs[tid] = rsqrtf(fmaxf(s2 * (1.f / 256.f) - m * m, 0.f) + 1e-5f);
  }
  __syncthreads();
  const long ctok = (long)b * 2048 + tok0 + cj;
#pragma unroll
  for (int g = 0; g < 4; ++g) {
    int c = g * 32 + cr;
    short8 v0 = *(const short8*)&tile[c][cj];
    short8 v1 = *(const short8*)&tile[c + 128][cj];
    const bf16* cop = csT + (long)(c * 2) * 16384 + ctok;
    short8 co8 = *(const short8*)cop;
    short8 si8 = *(const short8*)(cop + 16384);
    short8 o0, o1;
#pragma unroll
    for (int e = 0; e < 8; ++e) {
      float m = smu[cj + e], r = srs[cj + e];
      float a = (us2f((unsigned short)v0[e]) - m) * r;
      float bb = (us2f((unsigned short)v1[e]) - m) * r;
      float co = us2f((unsigned short)co8[e]);
      float si = us2f((unsigned short)si8[e]);
      bf16 t0 = __float2bfloat16(a * co - bb * si);
      bf16 t1 = __float2bfloat16(bb * co + a * si);
      o0[e] = *(short*)&t0; o1[e] = *(short*)&t1;
    }
    *(short8*)&base[(long)c * 2048 + cj] = o0;
    *(short8*)&base[(long)(c + 128) * 2048 + cj] = o1;
  }
}

// token-major instnorm + rotary (4 tokens/block); in may equal out
__global__ void __launch_bounds__(256) k_rotq(
    const bf16* __restrict__ in, bf16* __restrict__ out, const bf16* __restrict__ cs) {
  __shared__ float xr[4][CC];
  __shared__ float mu[4], rs[4];
  int tid = threadIdx.x;
  long tok0 = (long)blockIdx.x * 4;
#pragma unroll
  for (int t = 0; t < 4; ++t) xr[t][tid] = __bfloat162float(in[(tok0 + t) * 256 + tid]);
  stats_rows<4>(xr, mu, rs, 1e-5f);
  int i = tid & 127;
#pragma unroll
  for (int t = 0; t < 4; ++t) {
    float co = __bfloat162float(cs[(tok0 + t) * 256 + i]);
    float si = __bfloat162float(cs[(tok0 + t) * 256 + 128 + i]);
    float n0 = (xr[t][tid] - mu[t]) * rs[t];
    float n1 = (xr[t][tid ^ 128] - mu[t]) * rs[t];
    float o = (tid < 128) ? (n0 * co - n1 * si) : (n0 * co + n1 * si);
    out[(tok0 + t) * 256 + tid] = __float2bfloat16(o);
  }
}

// ---------------- weight prep: 12 transposes, one kernel --------------------
struct WEnt { const float* s; bf16* d; int K; int N; int blk0; };
struct WTab { WEnt e[12]; };

__global__ void __launch_bounds__(256) k_wprep(WTab t) {
  int bid = blockIdx.x;
  int ei = 0;
#pragma unroll
  for (int i = 1; i < 12; ++i)
    if (bid >= t.e[i].blk0) ei = i;
  WEnt e = t.e[ei];
  int local = (bid - e.blk0) * 256 + threadIdx.x;
  if (local < e.K * e.N) {
    int n = local / e.K, k = local - n * e.K;
    e.d[local] = __float2bfloat16(e.s[(long)k * e.N + n]);
  }
}

// ---------------- k_csT: transposed cos/sin table, coalesced writes ---------
__global__ void __launch_bounds__(256) k_csT(
    const float* __restrict__ pos, bf16* __restrict__ csT) {
  const int c = blockIdx.y;
  const int n = blockIdx.x * 256 + threadIdx.x;
  float inv = exp2f(-((float)c * (1.f / 128.f)) * LOG2_1E4);
  float fh = pos[n] * 2048.f * inv;
  float s, co; sincosf(fh, &s, &co);
  csT[(long)(c * 2) * 16384 + n] = __float2bfloat16(co);
  csT[(long)(c * 2 + 1) * 16384 + n] = __float2bfloat16(s);
}

// ---------------- k_pre: fourier feats, token-major cos/sin, pvec, z->bf16 --
__global__ void __launch_bounds__(256) k_pre(
    const float* __restrict__ pos, const float* __restrict__ Bf,
    const float* __restrict__ z, const float* __restrict__ P1,
    bf16* __restrict__ gf, bf16* __restrict__ cs,
    float* __restrict__ pvec, bf16* __restrict__ zb, float* __restrict__ P1L) {
  int tid = threadIdx.x;
  long tok0 = (long)blockIdx.x * 4;
  if (blockIdx.x == 0) P1L[tid] = P1[65536 + tid];
  float p[4];
#pragma unroll
  for (int t = 0; t < 4; ++t) p[t] = pos[tok0 + t];
  if (tid < 4) pvec[tok0 + tid] = p[tid] * 0.0625f;
  float bfc = Bf[tid];
#pragma unroll
  for (int t = 0; t < 4; ++t) {
    float xp = TWO_PI * (p[t] * 0.0625f) * bfc;
    float s, c; sincosf(xp, &s, &c);
    gf[(tok0 + t) * 512 + tid] = __float2bfloat16(gelu_f(s));
    gf[(tok0 + t) * 512 + 256 + tid] = __float2bfloat16(gelu_f(c));
    zb[(tok0 + t) * 256 + tid] = __float2bfloat16(z[(tok0 + t) * 256 + tid]);
  }
  if (tid < 128) {
    float inv = exp2f(-((float)tid * (1.f / 128.f)) * LOG2_1E4);
#pragma unroll
    for (int t = 0; t < 4; ++t) {
      float fh = p[t] * 2048.f * inv;
      float s, c; sincosf(fh, &s, &c);
      cs[(tok0 + t) * 256 + tid] = __float2bfloat16(c);
      cs[(tok0 + t) * 256 + 128 + tid] = __float2bfloat16(s);
    }
  }
}

__global__ void __launch_bounds__(256) k_ln(
    const float* __restrict__ xin, const float* __restrict__ g,
    const float* __restrict__ b, bf16* __restrict__ hout) {
  __shared__ float xr[4][CC];
  __shared__ float mu[4], rs[4];
  int tid = threadIdx.x;
  long tok0 = (long)blockIdx.x * 4;
#pragma unroll
  for (int t = 0; t < 4; ++t) xr[t][tid] = xin[(tok0 + t) * 256 + tid];
  stats_rows<4>(xr, mu, rs, 1e-5f);
  float gv = g[tid], bv = b[tid];
#pragma unroll
  for (int t = 0; t < 4; ++t)
    hout[(tok0 + t) * 256 + tid] = __float2bfloat16((xr[t][tid] - mu[t]) * rs[t] * gv + bv);
}

__global__ void __launch_bounds__(256) k_final(
    const bf16* __restrict__ g2, const float* __restrict__ D3,
    const float* __restrict__ b3, float* __restrict__ u) {
  int w = threadIdx.x >> 6, l = threadIdx.x & 63;
  long tok = (long)blockIdx.x * 4 + w;
  float s = __bfloat162float(g2[tok * 128 + l]) * D3[l]
          + __bfloat162float(g2[tok * 128 + 64 + l]) * D3[64 + l];
#pragma unroll
  for (int o = 32; o; o >>= 1) s += __shfl_down(s, o);
  if (l == 0) u[tok] = s + b3[0];
}

// ======================= launcher ===========================================
extern "C" void kernel_launch(void* const* d_in, const int* in_sizes, int n_in,
                              void* d_out, int out_size, void* d_ws, size_t ws_size,
                              hipStream_t stream) {
  const float* z    = (const float*)d_in[0];
  const float* pos  = (const float*)d_in[1];
  const float* Bf   = (const float*)d_in[2];
  const float* Wc   = (const float*)d_in[3];
  const float* Wkv  = (const float*)d_in[4];
  const float* Woca = (const float*)d_in[5];
  const float* boca = (const float*)d_in[6];
  const float* Wf1  = (const float*)d_in[7];
  const float* bf1  = (const float*)d_in[8];
  const float* Wf2  = (const float*)d_in[9];
  const float* bf2  = (const float*)d_in[10];
  const float* lng  = (const float*)d_in[11];
  const float* lnb  = (const float*)d_in[12];
  const float* P1   = (const float*)d_in[13];
  const float* P2   = (const float*)d_in[14];
  const float* P3   = (const float*)d_in[15];
  const float* Wqkv = (const float*)d_in[16];
  const float* Woda = (const float*)d_in[17];
  const float* boda = (const float*)d_in[18];
  const float* ln2g = (const float*)d_in[19];
  const float* ln2b = (const float*)d_in[20];
  const float* D1   = (const float*)d_in[21];
  const float* D2   = (const float*)d_in[22];
  const float* D3   = (const float*)d_in[23];
  const float* b3   = (const float*)d_in[24];

  float* u  = (float*)d_out;
  float* zp = (float*)d_out + NTOK;

  const long MB = 1048576L;
  char* ws = (char*)d_ws;
  // ---- static region [0, 24MB) ----
  bf16*  cs   = (bf16*)(ws);
  bf16*  csT  = (bf16*)(ws + 8 * MB);
  float* pvec = (float*)(ws + 16 * MB);
  long wo = 16 * MB + 65536;
  bf16* WcT   = (bf16*)(ws + wo);               wo += 262144;
  bf16* WkvT  = (bf16*)(ws + wo);               wo += 1048576;
  bf16* WocaT = (bf16*)(ws + wo);               wo += 524288;
  bf16* Wf1T  = (bf16*)(ws + wo);               wo += 131072;
  bf16* Wf2T  = (bf16*)(ws + wo);               wo += 131072;
  bf16* P1T   = (bf16*)(ws + wo);               wo += 131072;
  bf16* P2T   = (bf16*)(ws + wo);               wo += 131072;
  bf16* P3T   = (bf16*)(ws + wo);               wo += 131072;
  bf16* WqkvT = (bf16*)(ws + wo);               wo += 393216;
  bf16* WodaT = (bf16*)(ws + wo);               wo += 131072;
  bf16* D1T   = (bf16*)(ws + wo);               wo += 131072;
  bf16* D2T   = (bf16*)(ws + wo);               wo += 65536;
  float* P1L  = (float*)(ws + wo);              wo += 1024;
  // ---- dynamic arena at 24 MB (lifetime-audited; overlaps only across
  //      sequential launches). x2 f32 removed this round; zpb extends to R22.
  char* AR = ws + 24 * MB;
  bf16*  xb     = (bf16*)(AR);             // [0,8)   W4  R9'
  bf16*  zb     = (bf16*)(AR + 8 * MB);    // [8,16)  W2  R5
  bf16*  gf     = (bf16*)(AR + 48 * MB);   // [48,64) W2  R4 (Vt W5 after)
  bf16*  Kt     = (bf16*)(AR + 16 * MB);   // [16,48) W5/6 R7
  bf16*  Vt     = (bf16*)(AR + 48 * MB);   // [48,80) W5  R7
  bf16*  dotsH  = (bf16*)(AR + 8 * MB);    // [8,12)  W7  R8b
  bf16*  MwT    = (bf16*)(AR + 12 * MB);   // [12,13) W8b R9'
  bf16*  qrot   = (bf16*)(AR + 16 * MB);   // [16,24) W8  R9'
  bf16*  x2b    = (bf16*)(AR + 72 * MB);   // [72,80) W9' R11 (k2t W17 after)
  bf16*  t1     = (bf16*)(AR + 24 * MB);   // [24,32) W10 R11
  float* x3     = (float*)(AR + 32 * MB);  // [32,48) W11 R15 (f32)
  bf16*  h      = (bf16*)(AR + 16 * MB);   // [16,24) W12 R13
  bf16*  p1o    = (bf16*)(AR + 24 * MB);   // [24,32) W13 R14
  bf16*  p2o    = (bf16*)(AR + 48 * MB);   // [48,56) W14 R15
  bf16*  zpb    = (bf16*)(AR + 56 * MB);   // [56,64) W15 R22 (zd residual)
  bf16*  q2b    = (bf16*)(AR + 64 * MB);   // [64,72) W16/18 R21
  bf16*  k2t    = (bf16*)(AR + 72 * MB);   // [72,80) W17/19 R20
  bf16*  v2t    = (bf16*)(AR + 8 * MB);    // [8,16)  W17 R20
  bf16*  dots2T = (bf16*)(AR + 16 * MB);   // [16,17) W20 R21
  bf16*  att    = (bf16*)(AR + 24 * MB);   // [24,32) W21 R22
  float* zd     = (float*)(AR + 32 * MB);  // [32,48) W22 R23 (x3 R15 done)
  bf16*  h2     = (bf16*)(AR + 8 * MB);    // [8,16)  W23 R24
  bf16*  g1     = (bf16*)(AR + 16 * MB);   // [16,24) W24 R25
  bf16*  g2     = (bf16*)(AR + 24 * MB);   // [24,28) W25 R26

  // ---- weight-prep table ----
  WTab tab;
  int nb = 0;
  auto add = [&](int i, const float* s, bf16* d, int K_, int N_) {
    tab.e[i].s = s; tab.e[i].d = d; tab.e[i].K = K_; tab.e[i].N = N_;
    tab.e[i].blk0 = nb; nb += (K_ * N_) / 256;
  };
  add(0, Wc, WcT, 512, 256);
  add(1, Wkv, WkvT, 256, 2048);
  add(2, Woca, WocaT, 1024, 256);
  add(3, Wf1, Wf1T, 256, 256);
  add(4, Wf2, Wf2T, 256, 256);
  add(5, P1, P1T, 256, 256);
  add(6, P2, P2T, 256, 256);
  add(7, P3, P3T, 256, 256);
  add(8, Wqkv, WqkvT, 256, 768);
  add(9, Woda, WodaT, 256, 256);
  add(10, D1, D1T, 256, 256);
  add(11, D2, D2T, 256, 128);
  k_wprep<<<nb, 256, 0, stream>>>(tab);                                       // 1

  k_pre<<<NTOK / 4, 256, 0, stream>>>(pos, Bf, z, P1, gf, cs, pvec, zb, P1L); // 2
  k_csT<<<dim3(NTOK / 256, 128), 256, 0, stream>>>(pos, csT);                 // 3
  // 4: x = gelu(fourier) @ WcT
  k_gemm<512, E_BF16><<<dim3(4, 128, 1), 256, 0, stream>>>(
      gf, 512, WcT, 0, 0, 0, 0, nullptr, nullptr, nullptr, nullptr, nullptr,
      nullptr, xb, 256);
  // 5: Kt/Vt = (z @ Wkv) transposed per (b,h)
  k_gemmT<256><<<32 * 128, 256, 0, stream>>>(zb, 256, WkvT, 32, Kt, Vt, 1024, 4);
  // 6: fused instnorm + rotary on Kt (in place)
  k_normrot<<<dim3(32, 32), 256, 0, stream>>>(Kt, csT, 2);
  // 7: dotsH[b][d][h*256+e] = (Vt*Kt^T/n) untransposed, H-concat along K
  k_atb2<<<512, 256, 0, stream>>>(Vt, Kt, dotsH, 1.f / 2048.f, 1);
  // 8: qrot
  k_rotq<<<NTOK / 4, 256, 0, stream>>>(xb, qrot, cs);
  // 8b: MwT[b] = WocaT @ dotsH[b]  (head-sum pre-multiply)
  k_gemm<1024, E_BF16><<<dim3(4, 2, 8), 256, 0, stream>>>(
      WocaT, 1024, dotsH, 0, 262144L, 0, 65536L, nullptr, nullptr, nullptr,
      nullptr, nullptr, nullptr, MwT, 256);
  // 9': x2b = bf16(qrot @ MwT[b] + boca + x)   (f32 x2 eliminated)
  k_gemm<256, E_BIAS_RESB_BF16><<<dim3(4, 128, 1), 256, 0, stream>>>(
      qrot, 256, MwT, 65536L, 0, 0, 0, boca, nullptr, xb, nullptr, nullptr,
      nullptr, x2b, 256);
  // 10: t1 = gelu(x2b @ Wf1 + bf1)
  k_gemm<256, E_BIAS_GELU><<<dim3(4, 128, 1), 256, 0, stream>>>(
      x2b, 256, Wf1T, 0, 0, 0, 0, bf1, nullptr, nullptr, nullptr, nullptr,
      nullptr, t1, 256);
  // 11: x3 = t1 @ Wf2 + bf2 + x2b   (bf16 residual)
  k_gemm<256, E_BIAS_RESB_F32><<<dim3(4, 128, 1), 256, 0, stream>>>(
      t1, 256, Wf2T, 0, 0, 0, 0, bf2, nullptr, x2b, nullptr, nullptr,
      x3, nullptr, 256);
  k_ln<<<NTOK / 4, 256, 0, stream>>>(x3, lng, lnb, h);                        // 12
  // 13: p1o = gelu(h @ P1T + pvec*P1L)
  k_gemm<256, E_RANK1_GELU><<<dim3(4, 128, 1), 256, 0, stream>>>(
      h, 256, P1T, 0, 0, 0, 0, nullptr, nullptr, nullptr, P1L, pvec,
      nullptr, p1o, 256);
  // 14
  k_gemm<256, E_GELU><<<dim3(4, 128, 1), 256, 0, stream>>>(
      p1o, 256, P2T, 0, 0, 0, 0, nullptr, nullptr, nullptr, nullptr, nullptr,
      nullptr, p2o, 256);
  // 15: zp = p2o @ P3T + x3  (x3 residual stays f32: zp is a graded output)
  k_gemm<256, E_RES_BOTH><<<dim3(4, 128, 1), 256, 0, stream>>>(
      p2o, 256, P3T, 0, 0, 0, 0, nullptr, x3, nullptr, nullptr, nullptr,
      zp, zpb, 256);
  // 16: q2 token-major
  k_gemm<256, E_BF16><<<dim3(4, 128, 1), 256, 0, stream>>>(
      zpb, 256, WqkvT, 0, 0, 0, 0, nullptr, nullptr, nullptr, nullptr, nullptr,
      nullptr, q2b, 256);
  // 17: k2/v2 transposed
  k_gemmT<256><<<8 * 128, 256, 0, stream>>>(zpb, 256, WqkvT + 65536, 8, k2t, v2t, 256, 1);
  k_rotq<<<NTOK / 4, 256, 0, stream>>>(q2b, q2b, cs);                         // 18
  k_normrot<<<dim3(32, 8), 256, 0, stream>>>(k2t, csT, 0);                    // 19
  k_atb2<<<128, 256, 0, stream>>>(v2t, k2t, dots2T, 1.f / 2048.f, 0);         // 20
  // 21: att = q2' @ dots2T[b]
  k_gemm<256, E_BF16><<<dim3(4, 128, 1), 256, 0, stream>>>(
      q2b, 256, dots2T, 65536L, 0, 0, 0, nullptr, nullptr, nullptr, nullptr,
      nullptr, nullptr, att, 256);
  // 22: zd = att @ WodaT + boda + zpb   (bf16 residual replaces f32 zp read)
  k_gemm<256, E_BIAS_RESB_F32><<<dim3(4, 128, 1), 256, 0, stream>>>(
      att, 256, WodaT, 0, 0, 0, 0, boda, nullptr, zpb, nullptr, nullptr,
      zd, nullptr, 256);
  k_ln<<<NTOK / 4, 256, 0, stream>>>(zd, ln2g, ln2b, h2);                     // 23
  // 24
  k_gemm<256, E_GELU><<<dim3(4, 128, 1), 256, 0, stream>>>(
      h2, 256, D1T, 0, 0, 0, 0, nullptr, nullptr, nullptr, nullptr, nullptr,
      nullptr, g1, 256);
  // 25
  k_gemm<256, E_GELU><<<dim3(2, 128, 1), 256, 0, stream>>>(
      g1, 256, D2T, 0, 0, 0, 0, nullptr, nullptr, nullptr, nullptr, nullptr,
      nullptr, g2, 128);
  k_final<<<NTOK / 4, 256, 0, stream>>>(g2, D3, b3, u);                       // 26
}

// Round 17
// 383.377 us; speedup vs baseline: 1.2522x; 1.0095x over previous
//
#include <hip/hip_runtime.h>
#include <hip/hip_bf16.h>

using bf16 = __hip_bfloat16;
typedef __attribute__((ext_vector_type(8))) short short8;
typedef __attribute__((ext_vector_type(4))) short short4v;
typedef __attribute__((ext_vector_type(4))) float f32x4;

constexpr int BB = 8;
constexpr int NN = 2048;
constexpr int CC = 256;
constexpr int NTOK = BB * NN;  // 16384
constexpr float TWO_PI = 6.283185307179586f;
constexpr float LOG2_1E4 = 13.287712379549449f;

__device__ __forceinline__ float gelu_f(float x) {
  return 0.5f * x * (1.0f + erff(x * 0.7071067811865475f));
}
__device__ __forceinline__ float us2f(unsigned short u) {
  return __uint_as_float(((unsigned)u) << 16);
}
__device__ __forceinline__ int xcd_swz(int f, int nwg) {
  return (f & 7) * (nwg >> 3) + (f >> 3);
}

template <int T>
__device__ __forceinline__ void stats_rows(const float (*buf)[CC], float* mu, float* rs, float eps) {
  __syncthreads();
  int w = threadIdx.x >> 6, l = threadIdx.x & 63;
  if (w < T) {
    float s = 0.f, s2 = 0.f;
#pragma unroll
    for (int j = 0; j < 4; ++j) { float v = buf[w][l + 64 * j]; s += v; s2 += v * v; }
#pragma unroll
    for (int o = 32; o; o >>= 1) { s += __shfl_down(s, o); s2 += __shfl_down(s2, o); }
    if (l == 0) {
      float m = s * (1.f / 256.f);
      float var = fmaxf(s2 * (1.f / 256.f) - m * m, 0.f);
      mu[w] = m; rs[w] = rsqrtf(var + eps);
    }
  }
  __syncthreads();
}

// ---------------- shared MFMA GEMM core (pointer-LDS, XOR-swizzled) ---------
#define GLD16(src, dst)                                                       \
  __builtin_amdgcn_global_load_lds(                                           \
      (const __attribute__((address_space(1))) void*)(src),                   \
      (__attribute__((address_space(3))) void*)(dst), 16, 0, 0)

template <int K, int MI, int NB>
__device__ __forceinline__ void gemm_core(
    const bf16* __restrict__ Ap, int lda, const bf16* __restrict__ Bp,
    bf16* As, bf16* Bs, f32x4 (&acc)[MI][2]) {
  constexpr int ASTR = MI * 32 * 64;
  const int tid = threadIdx.x;
  const int w = tid >> 6, l = tid & 63;
  const int srow = l >> 3;
  const int scol = ((l & 7) ^ srow) * 8;
  const int rsw = (l & 7) * 8;
  const int wm = w >> 1, wn = w & 1;

  auto stage_tile = [&](int buf, int kt) {
    bf16* A_ = As + buf * ASTR;
    bf16* B_ = Bs + buf * 4096;
#pragma unroll
    for (int i = 0; i < MI; ++i) {
      int r = (w * MI + i) * 8 + srow;
      GLD16(Ap + (long)r * lda + kt + scol, &A_[(w * MI + i) * 512 + l * 8]);
    }
#pragma unroll
    for (int i = 0; i < 2; ++i) {
      int r = (w * 2 + i) * 8 + srow;
      GLD16(Bp + (long)r * K + kt + scol, &B_[(w * 2 + i) * 512 + l * 8]);
    }
  };
  auto compute = [&](int buf) {
    const bf16* A_ = As + buf * ASTR;
    const bf16* B_ = Bs + buf * 4096;
    short8 bfr[2][2];
#pragma unroll
    for (int ni = 0; ni < 2; ++ni)
#pragma unroll
      for (int ks = 0; ks < 2; ++ks)
        bfr[ni][ks] = *(const short8*)&B_[(wn * 32 + ni * 16 + (l & 15)) * 64 +
                                          ((ks * 32 + (l >> 4) * 8) ^ rsw)];
#pragma unroll
    for (int mi = 0; mi < MI; ++mi) {
#pragma unroll
      for (int ks = 0; ks < 2; ++ks) {
        short8 afr = *(const short8*)&A_[(wm * (MI * 16) + mi * 16 + (l & 15)) * 64 +
                                         ((ks * 32 + (l >> 4) * 8) ^ rsw)];
#pragma unroll
        for (int ni = 0; ni < 2; ++ni)
          acc[mi][ni] = __builtin_amdgcn_mfma_f32_16x16x32_bf16(afr, bfr[ni][ks], acc[mi][ni], 0, 0, 0);
      }
    }
  };

  if constexpr (NB == 2) {
    stage_tile(0, 0);
    asm volatile("s_waitcnt vmcnt(0)" ::: "memory");
    __builtin_amdgcn_s_barrier();
    int cur = 0;
    for (int kt = 0; kt < K; kt += 64) {
      const bool more = (kt + 64 < K);
      if (more) stage_tile(cur ^ 1, kt + 64);
      compute(cur);
      if (more) asm volatile("s_waitcnt vmcnt(0)" ::: "memory");
      __builtin_amdgcn_s_barrier();
      cur ^= 1;
    }
  } else {
    for (int kt = 0; kt < K; kt += 64) {
      stage_tile(0, kt);
      __syncthreads();
      compute(0);
      __syncthreads();
    }
  }
}

// ---------------- GEMM body (BM=128, BN=64) with fused epilogues ------------
enum { E_BF16 = 0, E_BIAS_RESB_BF16, E_BIAS_GELU, E_BIAS_RESB_F32,
       E_RANK1_GELU, E_GELU, E_RES_BOTH };

template <int K, int EPI>
__device__ __forceinline__ void gemm_body(
    int m0, int n0, int zidx,
    const bf16* __restrict__ A, int lda, const bf16* __restrict__ Bt,
    long bstride, long zstride, int nOffZ, long ozstride,
    const float* __restrict__ bias, const float* __restrict__ res,
    const bf16* __restrict__ resB, const float* __restrict__ rank1,
    const float* __restrict__ pvec,
    float* __restrict__ outF, bf16* __restrict__ outB, int ldo,
    bf16* As, bf16* Bs) {
  const int tid = threadIdx.x;
  const int w = tid >> 6, l = tid & 63;
  const int bidx = m0 >> 11;
  const bf16* Bp = Bt + (long)bidx * bstride + (long)zidx * zstride + (long)n0 * K;
  f32x4 acc[4][2] = {};
  gemm_core<K, 4, 1>(A + (long)m0 * lda, lda, Bp, As, Bs, acc);
  const int wm = w >> 1, wn = w & 1;
  const int zoff = zidx * nOffZ;
  const long ozoff = (long)zidx * ozstride;
#pragma unroll
  for (int mi = 0; mi < 4; ++mi) {
#pragma unroll
    for (int ni = 0; ni < 2; ++ni) {
      const int bcol = n0 + wn * 32 + ni * 16 + (l & 15);
      const int ocol = bcol + zoff;
#pragma unroll
      for (int r = 0; r < 4; ++r) {
        const int row = m0 + wm * 64 + mi * 16 + (l >> 4) * 4 + r;
        float v = acc[mi][ni][r];
        const long oidx = (long)row * ldo + ocol + ozoff;
        if constexpr (EPI == E_BF16) { outB[oidx] = __float2bfloat16(v); }
        else if constexpr (EPI == E_BIAS_RESB_BF16) {
          v += bias[bcol] + __bfloat162float(resB[oidx]);
          outB[oidx] = __float2bfloat16(v);
        } else if constexpr (EPI == E_BIAS_GELU) {
          v = gelu_f(v + bias[bcol]); outB[oidx] = __float2bfloat16(v);
        } else if constexpr (EPI == E_BIAS_RESB_F32) {
          v += bias[bcol] + __bfloat162float(resB[oidx]);
          outF[oidx] = v;
        } else if constexpr (EPI == E_RANK1_GELU) {
          v = gelu_f(v + pvec[row] * rank1[bcol]); outB[oidx] = __float2bfloat16(v);
        } else if constexpr (EPI == E_GELU) {
          v = gelu_f(v); outB[oidx] = __float2bfloat16(v);
        } else {  // E_RES_BOTH
          v += res[oidx]; outF[oidx] = v; outB[oidx] = __float2bfloat16(v);
        }
      }
    }
  }
}

template <int K, int EPI>
__global__ void __launch_bounds__(256) k_gemm(
    const bf16* __restrict__ A, int lda, const bf16* __restrict__ Bt,
    long bstride, long zstride, int nOffZ, long ozstride,
    const float* __restrict__ bias, const float* __restrict__ res,
    const bf16* __restrict__ resB, const float* __restrict__ rank1,
    const float* __restrict__ pvec,
    float* __restrict__ outF, bf16* __restrict__ outB, int ldo) {
  __shared__ bf16 lds[12288];
  gemm_body<K, EPI>(blockIdx.y * 128, blockIdx.x * 64, blockIdx.z,
                    A, lda, Bt, bstride, zstride, nOffZ, ozstride,
                    bias, res, resB, rank1, pvec, outF, outB, ldo,
                    lds, lds + 8192);
}

// ---------------- gemmT body: GEMM + transposed per-matrix store ------------
template <int K>
__device__ __forceinline__ void gemmT_body(
    int m0, int n0, const bf16* __restrict__ A, int lda,
    const bf16* __restrict__ Bt, bf16* __restrict__ T0, bf16* __restrict__ T1,
    int thresh, int matsPerB, bf16* lds) {
  const int tid = threadIdx.x;
  const int w = tid >> 6, l = tid & 63;
  f32x4 acc[4][2] = {};
  gemm_core<K, 4, 1>(A + (long)m0 * lda, lda, Bt + (long)n0 * K, lds, lds + 8192, acc);
  const int wm = w >> 1, wn = w & 1;
  __syncthreads();
  bf16* stage = lds;  // 64*132 = 8448 elems (fits in 12288)
#pragma unroll
  for (int mi = 0; mi < 4; ++mi)
#pragma unroll
    for (int ni = 0; ni < 2; ++ni) {
      int c = wn * 32 + ni * 16 + (l & 15);
      int row0 = wm * 64 + mi * 16 + (l >> 4) * 4;
#pragma unroll
      for (int q = 0; q < 2; ++q) {
        bf16 b0 = __float2bfloat16(acc[mi][ni][2 * q]);
        bf16 b1 = __float2bfloat16(acc[mi][ni][2 * q + 1]);
        unsigned u = (unsigned)*(unsigned short*)&b0 |
                     ((unsigned)*(unsigned short*)&b1 << 16);
        *(unsigned*)&stage[c * 132 + row0 + 2 * q] = u;
      }
    }
  __syncthreads();
  const int b = m0 >> 11, nbase = m0 & 2047;
  const int part = (n0 >= thresh) ? 1 : 0;
  const int cT0 = n0 - (part ? thresh : 0);
  bf16* dst = (part ? T1 : T0) + ((long)(b * matsPerB + (cT0 >> 8))) * 524288
            + (long)(cT0 & 255) * 2048;
  const int c = tid >> 2, ns = tid & 3;
  bf16* rowp = dst + (long)c * 2048 + nbase + ns * 8;
#pragma unroll
  for (int j = 0; j < 4; ++j) {
    short4v lo = *(const short4v*)&stage[c * 132 + ns * 8 + j * 32];
    short4v hi = *(const short4v*)&stage[c * 132 + ns * 8 + j * 32 + 4];
    short8 v;
    v[0] = lo[0]; v[1] = lo[1]; v[2] = lo[2]; v[3] = lo[3];
    v[4] = hi[0]; v[5] = hi[1]; v[6] = hi[2]; v[7] = hi[3];
    *(short8*)&rowp[j * 32] = v;
  }
}

template <int K>
__global__ void __launch_bounds__(256) k_gemmT(
    const bf16* __restrict__ A, int lda, const bf16* __restrict__ Bt, int nx,
    bf16* __restrict__ T0, bf16* __restrict__ T1, int thresh, int matsPerB) {
  __shared__ bf16 lds[12288];
  const int f = xcd_swz(blockIdx.x, gridDim.x);
  gemmT_body<K>((f / nx) * 128, (f % nx) * 64, A, lda, Bt, T0, T1, thresh,
                matsPerB, lds);
}

// ---------------- k_atb2: per-mat A[256,2048] @ B[256,2048]^T ---------------
__global__ void __launch_bounds__(256) k_atb2(
    const bf16* __restrict__ A0, const bf16* __restrict__ B0,
    bf16* __restrict__ D0, float scale, int hconcat) {
  __shared__ bf16 As[2 * 2 * 32 * 64];
  __shared__ bf16 Bs[2 * 4096];
  const int tid = threadIdx.x;
  const int w = tid >> 6, l = tid & 63;
  const int f = xcd_swz(blockIdx.x, gridDim.x);
  const int n0 = (f & 3) * 64;
  const int m0 = ((f >> 2) & 3) * 64;
  const int mat = f >> 4;
  const bf16* Ap = A0 + (long)mat * 524288 + (long)m0 * 2048;
  const bf16* Bp = B0 + (long)mat * 524288 + (long)n0 * 2048;
  f32x4 acc[2][2] = {};
  gemm_core<2048, 2, 2>(Ap, 2048, Bp, As, Bs, acc);
  const int wm = w >> 1, wn = w & 1;
  if (hconcat) {
    const int b = mat >> 2, h = mat & 3;
    bf16* D = D0 + (long)b * 262144 + h * 256;
#pragma unroll
    for (int mi = 0; mi < 2; ++mi)
#pragma unroll
      for (int ni = 0; ni < 2; ++ni) {
        int col = n0 + wn * 32 + ni * 16 + (l & 15);
#pragma unroll
        for (int r = 0; r < 4; ++r) {
          int row = m0 + wm * 32 + mi * 16 + (l >> 4) * 4 + r;
          D[(long)col * 1024 + row] = __float2bfloat16(acc[mi][ni][r] * scale);
        }
      }
  } else {
    bf16* D = D0 + (long)mat * 65536;
#pragma unroll
    for (int mi = 0; mi < 2; ++mi)
#pragma unroll
      for (int ni = 0; ni < 2; ++ni) {
        int col = n0 + wn * 32 + ni * 16 + (l & 15);
#pragma unroll
        for (int r = 0; r < 4; ++r) {
          int row = m0 + wm * 32 + mi * 16 + (l >> 4) * 4 + r;
          D[(long)row * 256 + col] = __float2bfloat16(acc[mi][ni][r] * scale);
        }
      }
  }
}

// ---------------- normrot body (stats + norm + rotary, transposed tiles) ----
__device__ __forceinline__ void normrot_body(
    int xblk, int mat, bf16* __restrict__ Kt, const bf16* __restrict__ csT,
    int hshift, bf16 (*tile)[68], float (*ps)[64], float (*ps2)[64],
    float* smu, float* srs) {
  const int tok0 = xblk * 64;
  const int b = mat >> hshift;
  const int tid = threadIdx.x;
  bf16* base = Kt + (long)mat * 524288 + tok0;
  const int cr = tid >> 3;
  const int cj = (tid & 7) * 8;
#pragma unroll
  for (int g = 0; g < 8; ++g) {
    int c = g * 32 + cr;
    *(short8*)&tile[c][cj] = *(const short8*)&base[(long)c * 2048 + cj];
  }
  __syncthreads();
  {
    const int tk = tid & 63, q = tid >> 6;
    float s = 0.f, s2 = 0.f;
#pragma unroll 8
    for (int cc = 0; cc < 64; ++cc) {
      float v = us2f(*(const unsigned short*)&tile[q * 64 + cc][tk]);
      s += v; s2 += v * v;
    }
    ps[q][tk] = s; ps2[q][tk] = s2;
  }
  __syncthreads();
  if (tid < 64) {
    float s = ps[0][tid] + ps[1][tid] + ps[2][tid] + ps[3][tid];
    float s2 = ps2[0][tid] + ps2[1][tid] + ps2[2][tid] + ps2[3][tid];
    float m = s * (1.f / 256.f);
    smu[tid] = m;
    srs[tid] = rsqrtf(fmaxf(s2 * (1.f / 256.f) - m * m, 0.f) + 1e-5f);
  }
  __syncthreads();
  const long ctok = (long)b * 2048 + tok0 + cj;
#pragma unroll
  for (int g = 0; g < 4; ++g) {
    int c = g * 32 + cr;
    short8 v0 = *(const short8*)&tile[c][cj];
    short8 v1 = *(const short8*)&tile[c + 128][cj];
    const bf16* cop = csT + (long)(c * 2) * 16384 + ctok;
    short8 co8 = *(const short8*)cop;
    short8 si8 = *(const short8*)(cop + 16384);
    short8 o0, o1;
#pragma unroll
    for (int e = 0; e < 8; ++e) {
      float m = smu[cj + e], r = srs[cj + e];
      float a = (us2f((unsigned short)v0[e]) - m) * r;
      float bb = (us2f((unsigned short)v1[e]) - m) * r;
      float co = us2f((unsigned short)co8[e]);
      float si = us2f((unsigned short)si8[e]);
      bf16 t0 = __float2bfloat16(a * co - bb * si);
      bf16 t1 = __float2bfloat16(bb * co + a * si);
      o0[e] = *(short*)&t0; o1[e] = *(short*)&t1;
    }
    *(short8*)&base[(long)c * 2048 + cj] = o0;
    *(short8*)&base[(long)(c + 128) * 2048 + cj] = o1;
  }
}

struct NRS { bf16 tile[256][68]; float ps[4][64]; float ps2[4][64]; float smu[64]; float srs[64]; };

__global__ void __launch_bounds__(256) k_normrot(
    bf16* __restrict__ Kt, const bf16* __restrict__ csT, int hshift) {
  __shared__ NRS s;
  normrot_body(blockIdx.x, blockIdx.y, Kt, csT, hshift,
               s.tile, s.ps, s.ps2, s.smu, s.srs);
}

// ---------------- rotq body (token-major instnorm + rotary) -----------------
__device__ __forceinline__ void rotq_body(
    long tok0, const bf16* __restrict__ in, bf16* __restrict__ out,
    const bf16* __restrict__ cs, float (*xr)[CC], float* mu, float* rs) {
  int tid = threadIdx.x;
#pragma unroll
  for (int t = 0; t < 4; ++t) xr[t][tid] = __bfloat162float(in[(tok0 + t) * 256 + tid]);
  stats_rows<4>((const float(*)[CC])xr, mu, rs, 1e-5f);
  int i = tid & 127;
#pragma unroll
  for (int t = 0; t < 4; ++t) {
    float co = __bfloat162float(cs[(tok0 + t) * 256 + i]);
    float si = __bfloat162float(cs[(tok0 + t) * 256 + 128 + i]);
    float n0 = (xr[t][tid] - mu[t]) * rs[t];
    float n1 = (xr[t][tid ^ 128] - mu[t]) * rs[t];
    float o = (tid < 128) ? (n0 * co - n1 * si) : (n0 * co + n1 * si);
    out[(tok0 + t) * 256 + tid] = __float2bfloat16(o);
  }
}

struct RQS { float xr[4][CC]; float mu[4]; float rs[4]; };

// ---------------- merged kernels (independent pairs, disjoint R/W) ----------
// (A) k_pre + k_csT
__global__ void __launch_bounds__(256) k_pre_cst(
    const float* __restrict__ pos, const float* __restrict__ Bf,
    const float* __restrict__ z, const float* __restrict__ P1,
    bf16* __restrict__ gf, bf16* __restrict__ cs,
    float* __restrict__ pvec, bf16* __restrict__ zb, float* __restrict__ P1L,
    bf16* __restrict__ csT) {
  int tid = threadIdx.x;
  if (blockIdx.x < NTOK / 4) {
    long tok0 = (long)blockIdx.x * 4;
    if (blockIdx.x == 0) P1L[tid] = P1[65536 + tid];
    float p[4];
#pragma unroll
    for (int t = 0; t < 4; ++t) p[t] = pos[tok0 + t];
    if (tid < 4) pvec[tok0 + tid] = p[tid] * 0.0625f;
    float bfc = Bf[tid];
#pragma unroll
    for (int t = 0; t < 4; ++t) {
      float xp = TWO_PI * (p[t] * 0.0625f) * bfc;
      float s, c; sincosf(xp, &s, &c);
      gf[(tok0 + t) * 512 + tid] = __float2bfloat16(gelu_f(s));
      gf[(tok0 + t) * 512 + 256 + tid] = __float2bfloat16(gelu_f(c));
      zb[(tok0 + t) * 256 + tid] = __float2bfloat16(z[(tok0 + t) * 256 + tid]);
    }
    if (tid < 128) {
      float inv = exp2f(-((float)tid * (1.f / 128.f)) * LOG2_1E4);
#pragma unroll
      for (int t = 0; t < 4; ++t) {
        float fh = p[t] * 2048.f * inv;
        float s, c; sincosf(fh, &s, &c);
        cs[(tok0 + t) * 256 + tid] = __float2bfloat16(c);
        cs[(tok0 + t) * 256 + 128 + tid] = __float2bfloat16(s);
      }
    }
  } else {
    int idx = blockIdx.x - NTOK / 4;   // [0, 8192)
    int c = idx >> 6;
    int n = (idx & 63) * 256 + tid;
    float inv = exp2f(-((float)c * (1.f / 128.f)) * LOG2_1E4);
    float fh = pos[n] * 2048.f * inv;
    float s, co; sincosf(fh, &s, &co);
    csT[(long)(c * 2) * 16384 + n] = __float2bfloat16(co);
    csT[(long)(c * 2 + 1) * 16384 + n] = __float2bfloat16(s);
  }
}

// (B) qrot (4096 blocks) + Mw pre-multiply GEMM (64 blocks)
__global__ void __launch_bounds__(256) k_q8(
    const bf16* __restrict__ xb, bf16* __restrict__ qrot, const bf16* __restrict__ cs,
    const bf16* __restrict__ WocaT, const bf16* __restrict__ dotsH,
    bf16* __restrict__ MwT) {
  __shared__ union { bf16 lds[12288]; RQS rq; } sm;
  if (blockIdx.x < NTOK / 4) {
    rotq_body((long)blockIdx.x * 4, xb, qrot, cs, sm.rq.xr, sm.rq.mu, sm.rq.rs);
  } else {
    int g = blockIdx.x - NTOK / 4;   // [0, 64)
    gemm_body<1024, E_BF16>(((g >> 2) & 1) * 128, (g & 3) * 64, g >> 3,
                            WocaT, 1024, dotsH, 0, 262144L, 0, 65536L,
                            nullptr, nullptr, nullptr, nullptr, nullptr,
                            nullptr, MwT, 256, sm.lds, sm.lds + 8192);
  }
}

// (C) q2 token-major GEMM (512 blocks) + k2/v2 gemmT (1024 blocks)
__global__ void __launch_bounds__(256) k_qkv2(
    const bf16* __restrict__ zpb, const bf16* __restrict__ WqkvT,
    bf16* __restrict__ q2b, bf16* __restrict__ k2t, bf16* __restrict__ v2t) {
  __shared__ bf16 lds[12288];
  if (blockIdx.x < 512) {
    int f = blockIdx.x;
    gemm_body<256, E_BF16>((f >> 2) * 128, (f & 3) * 64, 0,
                           zpb, 256, WqkvT, 0, 0, 0, 0,
                           nullptr, nullptr, nullptr, nullptr, nullptr,
                           nullptr, q2b, 256, lds, lds + 8192);
  } else {
    int g = blockIdx.x - 512;        // [0, 1024)
    int fsw = xcd_swz(g, 1024);
    gemmT_body<256>((fsw / 8) * 128, (fsw % 8) * 64, zpb, 256,
                    WqkvT + 65536, k2t, v2t, 256, 1, lds);
  }
}

// (D) q2 rotq in place (4096) + k2 normrot (256)
__global__ void __launch_bounds__(256) k_rot2(
    bf16* __restrict__ q2b, const bf16* __restrict__ cs,
    bf16* __restrict__ k2t, const bf16* __restrict__ csT) {
  __shared__ union { RQS rq; NRS nr; } sm;
  if (blockIdx.x < NTOK / 4) {
    rotq_body((long)blockIdx.x * 4, q2b, q2b, cs, sm.rq.xr, sm.rq.mu, sm.rq.rs);
  } else {
    int idx = blockIdx.x - NTOK / 4;  // [0, 256)
    normrot_body(idx & 31, idx >> 5, k2t, csT, 0,
                 sm.nr.tile, sm.nr.ps, sm.nr.ps2, sm.nr.smu, sm.nr.srs);
  }
}

// ---------------- weight prep + k_ln + k_final ------------------------------
struct WEnt { const float* s; bf16* d; int K; int N; int blk0; };
struct WTab { WEnt e[12]; };

__global__ void __launch_bounds__(256) k_wprep(WTab t) {
  int bid = blockIdx.x;
  int ei = 0;
#pragma unroll
  for (int i = 1; i < 12; ++i)
    if (bid >= t.e[i].blk0) ei = i;
  WEnt e = t.e[ei];
  int local = (bid - e.blk0) * 256 + threadIdx.x;
  if (local < e.K * e.N) {
    int n = local / e.K, k = local - n * e.K;
    e.d[local] = __float2bfloat16(e.s[(long)k * e.N + n]);
  }
}

__global__ void __launch_bounds__(256) k_ln(
    const float* __restrict__ xin, const float* __restrict__ g,
    const float* __restrict__ b, bf16* __restrict__ hout) {
  __shared__ float xr[4][CC];
  __shared__ float mu[4], rs[4];
  int tid = threadIdx.x;
  long tok0 = (long)blockIdx.x * 4;
#pragma unroll
  for (int t = 0; t < 4; ++t) xr[t][tid] = xin[(tok0 + t) * 256 + tid];
  stats_rows<4>(xr, mu, rs, 1e-5f);
  float gv = g[tid], bv = b[tid];
#pragma unroll
  for (int t = 0; t < 4; ++t)
    hout[(tok0 + t) * 256 + tid] = __float2bfloat16((xr[t][tid] - mu[t]) * rs[t] * gv + bv);
}

__global__ void __launch_bounds__(256) k_final(
    const bf16* __restrict__ g2, const float* __restrict__ D3,
    const float* __restrict__ b3, float* __restrict__ u) {
  int w = threadIdx.x >> 6, l = threadIdx.x & 63;
  long tok = (long)blockIdx.x * 4 + w;
  float s = __bfloat162float(g2[tok * 128 + l]) * D3[l]
          + __bfloat162float(g2[tok * 128 + 64 + l]) * D3[64 + l];
#pragma unroll
  for (int o = 32; o; o >>= 1) s += __shfl_down(s, o);
  if (l == 0) u[tok] = s + b3[0];
}

// ======================= launcher ===========================================
extern "C" void kernel_launch(void* const* d_in, const int* in_sizes, int n_in,
                              void* d_out, int out_size, void* d_ws, size_t ws_size,
                              hipStream_t stream) {
  const float* z    = (const float*)d_in[0];
  const float* pos  = (const float*)d_in[1];
  const float* Bf   = (const float*)d_in[2];
  const float* Wc   = (const float*)d_in[3];
  const float* Wkv  = (const float*)d_in[4];
  const float* Woca = (const float*)d_in[5];
  const float* boca = (const float*)d_in[6];
  const float* Wf1  = (const float*)d_in[7];
  const float* bf1  = (const float*)d_in[8];
  const float* Wf2  = (const float*)d_in[9];
  const float* bf2  = (const float*)d_in[10];
  const float* lng  = (const float*)d_in[11];
  const float* lnb  = (const float*)d_in[12];
  const float* P1   = (const float*)d_in[13];
  const float* P2   = (const float*)d_in[14];
  const float* P3   = (const float*)d_in[15];
  const float* Wqkv = (const float*)d_in[16];
  const float* Woda = (const float*)d_in[17];
  const float* boda = (const float*)d_in[18];
  const float* ln2g = (const float*)d_in[19];
  const float* ln2b = (const float*)d_in[20];
  const float* D1   = (const float*)d_in[21];
  const float* D2   = (const float*)d_in[22];
  const float* D3   = (const float*)d_in[23];
  const float* b3   = (const float*)d_in[24];

  float* u  = (float*)d_out;
  float* zp = (float*)d_out + NTOK;

  const long MB = 1048576L;
  char* ws = (char*)d_ws;
  // ---- static region [0, 24MB) ----
  bf16*  cs   = (bf16*)(ws);
  bf16*  csT  = (bf16*)(ws + 8 * MB);
  float* pvec = (float*)(ws + 16 * MB);
  long wo = 16 * MB + 65536;
  bf16* WcT   = (bf16*)(ws + wo);               wo += 262144;
  bf16* WkvT  = (bf16*)(ws + wo);               wo += 1048576;
  bf16* WocaT = (bf16*)(ws + wo);               wo += 524288;
  bf16* Wf1T  = (bf16*)(ws + wo);               wo += 131072;
  bf16* Wf2T  = (bf16*)(ws + wo);               wo += 131072;
  bf16* P1T   = (bf16*)(ws + wo);               wo += 131072;
  bf16* P2T   = (bf16*)(ws + wo);               wo += 131072;
  bf16* P3T   = (bf16*)(ws + wo);               wo += 131072;
  bf16* WqkvT = (bf16*)(ws + wo);               wo += 393216;
  bf16* WodaT = (bf16*)(ws + wo);               wo += 131072;
  bf16* D1T   = (bf16*)(ws + wo);               wo += 131072;
  bf16* D2T   = (bf16*)(ws + wo);               wo += 65536;
  float* P1L  = (float*)(ws + wo);              wo += 1024;
  // ---- dynamic arena at 24 MB (lifetime-audited; merged launches have
  //      disjoint R/W sets per pair — see comments at merged kernels) ----
  char* AR = ws + 24 * MB;
  bf16*  xb     = (bf16*)(AR);             // [0,8)   W4  R8(q8)
  bf16*  zb     = (bf16*)(AR + 8 * MB);    // [8,16)  W2  R5
  bf16*  gf     = (bf16*)(AR + 48 * MB);   // [48,64) W2  R4 (Vt W5 after)
  bf16*  Kt     = (bf16*)(AR + 16 * MB);   // [16,48) W5/6 R7
  bf16*  Vt     = (bf16*)(AR + 48 * MB);   // [48,80) W5  R7
  bf16*  dotsH  = (bf16*)(AR + 8 * MB);    // [8,12)  W7  R8(q8)
  bf16*  MwT    = (bf16*)(AR + 12 * MB);   // [12,13) W8  R9
  bf16*  qrot   = (bf16*)(AR + 16 * MB);   // [16,24) W8  R9
  bf16*  x2b    = (bf16*)(AR + 72 * MB);   // [72,80) W9  R11 (k2t W16 after)
  bf16*  t1     = (bf16*)(AR + 24 * MB);   // [24,32) W10 R11
  float* x3     = (float*)(AR + 32 * MB);  // [32,48) W11 R15 (f32)
  bf16*  h      = (bf16*)(AR + 16 * MB);   // [16,24) W12 R13
  bf16*  p1o    = (bf16*)(AR + 24 * MB);   // [24,32) W13 R14
  bf16*  p2o    = (bf16*)(AR + 48 * MB);   // [48,56) W14 R15
  bf16*  zpb    = (bf16*)(AR + 56 * MB);   // [56,64) W15 R21 (zd residual)
  bf16*  q2b    = (bf16*)(AR + 64 * MB);   // [64,72) W16/17 R20
  bf16*  k2t    = (bf16*)(AR + 72 * MB);   // [72,80) W16/17 R19
  bf16*  v2t    = (bf16*)(AR + 8 * MB);    // [8,16)  W16 R19
  bf16*  dots2T = (bf16*)(AR + 16 * MB);   // [16,17) W19 R20
  bf16*  att    = (bf16*)(AR + 24 * MB);   // [24,32) W20 R21
  float* zd     = (float*)(AR + 32 * MB);  // [32,48) W21 R22 (x3 R15 done)
  bf16*  h2     = (bf16*)(AR + 8 * MB);    // [8,16)  W22 R23
  bf16*  g1     = (bf16*)(AR + 16 * MB);   // [16,24) W23 R24
  bf16*  g2     = (bf16*)(AR + 24 * MB);   // [24,28) W24 R25

  // ---- weight-prep table ----
  WTab tab;
  int nb = 0;
  auto add = [&](int i, const float* s, bf16* d, int K_, int N_) {
    tab.e[i].s = s; tab.e[i].d = d; tab.e[i].K = K_; tab.e[i].N = N_;
    tab.e[i].blk0 = nb; nb += (K_ * N_) / 256;
  };
  add(0, Wc, WcT, 512, 256);
  add(1, Wkv, WkvT, 256, 2048);
  add(2, Woca, WocaT, 1024, 256);
  add(3, Wf1, Wf1T, 256, 256);
  add(4, Wf2, Wf2T, 256, 256);
  add(5, P1, P1T, 256, 256);
  add(6, P2, P2T, 256, 256);
  add(7, P3, P3T, 256, 256);
  add(8, Wqkv, WqkvT, 256, 768);
  add(9, Woda, WodaT, 256, 256);
  add(10, D1, D1T, 256, 256);
  add(11, D2, D2T, 256, 128);
  k_wprep<<<nb, 256, 0, stream>>>(tab);                                       // 1

  // 2: k_pre + k_csT merged (independent; disjoint writes)
  k_pre_cst<<<NTOK / 4 + 8192, 256, 0, stream>>>(pos, Bf, z, P1, gf, cs, pvec,
                                                 zb, P1L, csT);
  // 4: x = gelu(fourier) @ WcT
  k_gemm<512, E_BF16><<<dim3(4, 128, 1), 256, 0, stream>>>(
      gf, 512, WcT, 0, 0, 0, 0, nullptr, nullptr, nullptr, nullptr, nullptr,
      nullptr, xb, 256);
  // 5: Kt/Vt = (z @ Wkv) transposed per (b,h)
  k_gemmT<256><<<32 * 128, 256, 0, stream>>>(zb, 256, WkvT, 32, Kt, Vt, 1024, 4);
  // 6: fused instnorm + rotary on Kt (in place)
  k_normrot<<<dim3(32, 32), 256, 0, stream>>>(Kt, csT, 2);
  // 7: dotsH[b][d][h*256+e] = (Vt*Kt^T/n) untransposed, H-concat along K
  k_atb2<<<512, 256, 0, stream>>>(Vt, Kt, dotsH, 1.f / 2048.f, 1);
  // 8: qrot + MwT merged (independent: xb->qrot | dotsH->MwT)
  k_q8<<<NTOK / 4 + 64, 256, 0, stream>>>(xb, qrot, cs, WocaT, dotsH, MwT);
  // 9: x2b = bf16(qrot @ MwT[b] + boca + x)
  k_gemm<256, E_BIAS_RESB_BF16><<<dim3(4, 128, 1), 256, 0, stream>>>(
      qrot, 256, MwT, 65536L, 0, 0, 0, boca, nullptr, xb, nullptr, nullptr,
      nullptr, x2b, 256);
  // 10: t1 = gelu(x2b @ Wf1 + bf1)
  k_gemm<256, E_BIAS_GELU><<<dim3(4, 128, 1), 256, 0, stream>>>(
      x2b, 256, Wf1T, 0, 0, 0, 0, bf1, nullptr, nullptr, nullptr, nullptr,
      nullptr, t1, 256);
  // 11: x3 = t1 @ Wf2 + bf2 + x2b
  k_gemm<256, E_BIAS_RESB_F32><<<dim3(4, 128, 1), 256, 0, stream>>>(
      t1, 256, Wf2T, 0, 0, 0, 0, bf2, nullptr, x2b, nullptr, nullptr,
      x3, nullptr, 256);
  k_ln<<<NTOK / 4, 256, 0, stream>>>(x3, lng, lnb, h);                        // 12
  // 13: p1o = gelu(h @ P1T + pvec*P1L)
  k_gemm<256, E_RANK1_GELU><<<dim3(4, 128, 1), 256, 0, stream>>>(
      h, 256, P1T, 0, 0, 0, 0, nullptr, nullptr, nullptr, P1L, pvec,
      nullptr, p1o, 256);
  // 14
  k_gemm<256, E_GELU><<<dim3(4, 128, 1), 256, 0, stream>>>(
      p1o, 256, P2T, 0, 0, 0, 0, nullptr, nullptr, nullptr, nullptr, nullptr,
      nullptr, p2o, 256);
  // 15: zp = p2o @ P3T + x3  (f32 residual; zp is a graded output)
  k_gemm<256, E_RES_BOTH><<<dim3(4, 128, 1), 256, 0, stream>>>(
      p2o, 256, P3T, 0, 0, 0, 0, nullptr, x3, nullptr, nullptr, nullptr,
      zp, zpb, 256);
  // 16: q2 GEMM + k2/v2 gemmT merged (both read zpb; disjoint writes)
  k_qkv2<<<512 + 1024, 256, 0, stream>>>(zpb, WqkvT, q2b, k2t, v2t);
  // 17: q2 rotq + k2 normrot merged (in-place on disjoint buffers)
  k_rot2<<<NTOK / 4 + 256, 256, 0, stream>>>(q2b, cs, k2t, csT);
  // 19: dots2T
  k_atb2<<<128, 256, 0, stream>>>(v2t, k2t, dots2T, 1.f / 2048.f, 0);
  // 20: att = q2' @ dots2T[b]
  k_gemm<256, E_BF16><<<dim3(4, 128, 1), 256, 0, stream>>>(
      q2b, 256, dots2T, 65536L, 0, 0, 0, nullptr, nullptr, nullptr, nullptr,
      nullptr, nullptr, att, 256);
  // 21: zd = att @ WodaT + boda + zpb
  k_gemm<256, E_BIAS_RESB_F32><<<dim3(4, 128, 1), 256, 0, stream>>>(
      att, 256, WodaT, 0, 0, 0, 0, boda, nullptr, zpb, nullptr, nullptr,
      zd, nullptr, 256);
  k_ln<<<NTOK / 4, 256, 0, stream>>>(zd, ln2g, ln2b, h2);                     // 22
  // 23
  k_gemm<256, E_GELU><<<dim3(4, 128, 1), 256, 0, stream>>>(
      h2, 256, D1T, 0, 0, 0, 0, nullptr, nullptr, nullptr, nullptr, nullptr,
      nullptr, g1, 256);
  // 24
  k_gemm<256, E_GELU><<<dim3(2, 128, 1), 256, 0, stream>>>(
      g1, 256, D2T, 0, 0, 0, 0, nullptr, nullptr, nullptr, nullptr, nullptr,
      nullptr, g2, 128);
  k_final<<<NTOK / 4, 256, 0, stream>>>(g2, D3, b3, u);                       // 25
}